// Round 1
// baseline (646.503 us; speedup 1.0000x reference)
//
#include <hip/hip_runtime.h>
#include <hip/hip_bf16.h>
#include <math.h>

#define NN 4096
#define EE 65536
#define HH 128
#define EDD 64
#define THD 512

typedef __bf16 bf16;
typedef __bf16 bf16x8 __attribute__((ext_vector_type(8)));
typedef __bf16 bf16x4 __attribute__((ext_vector_type(4)));
typedef float  floatx4 __attribute__((ext_vector_type(4)));

// ---------------------------------------------------------------------------
// input dtype detects (proven: floats f32, edge_index int32; cheap insurance)
// ---------------------------------------------------------------------------
__global__ __launch_bounds__(64) void k_detect(const void* __restrict__ p,
                                               int* __restrict__ flag)
{
    const bf16* b = (const bf16*)p;
    int t = threadIdx.x;
    int bad = 0;
    for (int i = 0; i < 32; i++) {
        float v = (float)b[t * 32 + i];
        if (!(v == v) || fabsf(v) > 100.f) bad = 1;
    }
    unsigned long long m = __ballot(bad);
    if (t == 0) *flag = (m == 0ULL) ? 1 : 0;
}

__global__ void k_canon_f(const void* __restrict__ src, float* __restrict__ dst,
                          int n, const int* __restrict__ flag)
{
    int i = blockIdx.x * 256 + threadIdx.x;
    if (i >= n) return;
    dst[i] = (*flag) ? (float)((const bf16*)src)[i] : ((const float*)src)[i];
}

__global__ void k_canon_b(const void* __restrict__ src, bf16* __restrict__ dst,
                          int n, const int* __restrict__ flag)
{
    int i = blockIdx.x * 256 + threadIdx.x;
    if (i >= n) return;
    dst[i] = (*flag) ? ((const bf16*)src)[i] : (bf16)((const float*)src)[i];
}

__global__ void k_canon_fb(const void* __restrict__ src, float* __restrict__ dst,
                           bf16* __restrict__ dst2, int n, const int* __restrict__ flag)
{
    int i = blockIdx.x * 256 + threadIdx.x;
    if (i >= n) return;
    float v = (*flag) ? (float)((const bf16*)src)[i] : ((const float*)src)[i];
    dst[i] = v;
    dst2[i] = (bf16)v;
}

// ea canon: CSR-ordered bf16 only (natural-order f32 copy was dead weight —
// the f32 ea is only needed as the FINAL output, written by layer-3 k_edge)
__global__ void k_canon_ea(const void* __restrict__ src,
                           bf16* __restrict__ eaord, const int* __restrict__ pos,
                           const int* __restrict__ flag)
{
    int i = blockIdx.x * 256 + threadIdx.x;   // E*64
    int e = i >> 6, d = i & 63;
    float v = (*flag) ? (float)((const bf16*)src)[i] : ((const float*)src)[i];
    eaord[(size_t)pos[e] * 64 + d] = (bf16)v;
}

__global__ __launch_bounds__(64) void k_detidx(const int* __restrict__ p,
                                               int* __restrict__ iflag)
{
    int t = threadIdx.x;
    int bad = 0;
    for (int i = 0; i < 8; i++) {
        int k = t * 8 + i;
        int lo = p[2 * k], hi = p[2 * k + 1];
        if (hi != 0 || lo < 0 || lo >= NN) bad = 1;
    }
    unsigned long long m = __ballot(bad);
    if (t == 0) *iflag = (m == 0ULL) ? 1 : 0;
}

__global__ void k_extidx(const int* __restrict__ p, int* __restrict__ srcW,
                         int* __restrict__ dstW, const int* __restrict__ iflag)
{
    int e = blockIdx.x * 256 + threadIdx.x;
    int s, d;
    if (*iflag) { s = p[2 * e];  d = p[2 * EE + 2 * e]; }
    else        { s = p[e];      d = p[EE + e]; }
    srcW[e] = min(max(s, 0), NN - 1);
    dstW[e] = min(max(d, 0), NN - 1);
}

// ---------------------------------------------------------------------------
// MFMA bf16 GEMM (validated): C[M,Nout] = act(A @ W^T + bias)
// ---------------------------------------------------------------------------
template<bool RELU, int OM>
__global__ __launch_bounds__(256) void k_mgemm(
    const bf16* __restrict__ A, int lda,
    const bf16* __restrict__ W, int ldw, const float* __restrict__ bias,
    void* __restrict__ Cv, int ldc, int K)
{
    __shared__ bf16 As[64][40];
    __shared__ bf16 Ws[64][40];
    const int m0 = blockIdx.x * 64, n0 = blockIdx.y * 64;
    const int tid = threadIdx.x, wave = tid >> 6, lane = tid & 63;
    const int wm = (wave & 1) * 32, wn = (wave >> 1) * 32;
    const int lrow = tid >> 2, lcol = (tid & 3) * 8;
    const int fr = lane & 15, fk = (lane >> 4) * 8;
    floatx4 acc00 = {0,0,0,0}, acc01 = {0,0,0,0}, acc10 = {0,0,0,0}, acc11 = {0,0,0,0};

    for (int k0 = 0; k0 < K; k0 += 32) {
        bf16x8 av = *(const bf16x8*)(A + (size_t)(m0 + lrow) * lda + k0 + lcol);
        bf16x8 wv = *(const bf16x8*)(W + (size_t)(n0 + lrow) * ldw + k0 + lcol);
        __syncthreads();
        *(bf16x8*)&As[lrow][lcol] = av;
        *(bf16x8*)&Ws[lrow][lcol] = wv;
        __syncthreads();
        bf16x8 a0 = *(const bf16x8*)&As[wm + fr][fk];
        bf16x8 a1 = *(const bf16x8*)&As[wm + 16 + fr][fk];
        bf16x8 b0 = *(const bf16x8*)&Ws[wn + fr][fk];
        bf16x8 b1 = *(const bf16x8*)&Ws[wn + 16 + fr][fk];
        acc00 = __builtin_amdgcn_mfma_f32_16x16x32_bf16(a0, b0, acc00, 0, 0, 0);
        acc01 = __builtin_amdgcn_mfma_f32_16x16x32_bf16(a0, b1, acc01, 0, 0, 0);
        acc10 = __builtin_amdgcn_mfma_f32_16x16x32_bf16(a1, b0, acc10, 0, 0, 0);
        acc11 = __builtin_amdgcn_mfma_f32_16x16x32_bf16(a1, b1, acc11, 0, 0, 0);
    }
    const int cc = lane & 15, cr = (lane >> 4) * 4;
    float vb0 = bias ? bias[n0 + wn + cc] : 0.f;
    float vb1 = bias ? bias[n0 + wn + 16 + cc] : 0.f;
    floatx4 accs[2][2] = {{acc00, acc01}, {acc10, acc11}};
#pragma unroll
    for (int mt = 0; mt < 2; mt++)
#pragma unroll
        for (int nt = 0; nt < 2; nt++) {
            float vb = nt ? vb1 : vb0;
#pragma unroll
            for (int i = 0; i < 4; i++) {
                int gm = m0 + wm + mt * 16 + cr + i;
                int gn = n0 + wn + nt * 16 + cc;
                float v = accs[mt][nt][i] + vb;
                if (RELU) v = fmaxf(v, 0.f);
                if (OM == 1) ((bf16*)Cv)[(size_t)gm * ldc + gn] = (bf16)v;
                else         ((float*)Cv)[(size_t)gm * ldc + gn] = v;
            }
        }
}

// ---------------------------------------------------------------------------
// Q GEMM, wide tile: Q_ord[E,512] = eaord[E,64] @ wcomb[512,64]^T
// ---------------------------------------------------------------------------
__global__ __launch_bounds__(256) void k_qgemm(
    const bf16* __restrict__ eaord, const bf16* __restrict__ wcomb,
    bf16* __restrict__ Qord)
{
    __shared__ bf16 As[64][72];
    __shared__ bf16 Ws[256][72];
    const int e0 = blockIdx.x * 64, n0g = blockIdx.y * 256;
    const int tid = threadIdx.x, wave = tid >> 6, lane = tid & 63;
    const int fr = lane & 15, fk = (lane >> 4) * 8;
    const int cc = lane & 15, cr = (lane >> 4) * 4;

#pragma unroll
    for (int v = 0; v < 2; v++) {
        int lin = v * 2048 + tid * 8;
        int r = lin >> 6, c = lin & 63;
        *(bf16x8*)&As[r][c] = *(const bf16x8*)(eaord + (size_t)(e0 + r) * 64 + c);
    }
#pragma unroll
    for (int v = 0; v < 8; v++) {
        int lin = v * 2048 + tid * 8;
        int r = lin >> 6, c = lin & 63;
        *(bf16x8*)&Ws[r][c] = *(const bf16x8*)(wcomb + (size_t)(n0g + r) * 64 + c);
    }
    __syncthreads();

    floatx4 acc[4][4];
#pragma unroll
    for (int mt = 0; mt < 4; mt++)
#pragma unroll
        for (int nt = 0; nt < 4; nt++) acc[mt][nt] = (floatx4){0,0,0,0};

#pragma unroll
    for (int kk = 0; kk < 64; kk += 32) {
        bf16x8 af[4], bv[4];
#pragma unroll
        for (int mt = 0; mt < 4; mt++) af[mt] = *(const bf16x8*)&As[mt * 16 + fr][kk + fk];
#pragma unroll
        for (int nt = 0; nt < 4; nt++) bv[nt] = *(const bf16x8*)&Ws[wave * 64 + nt * 16 + fr][kk + fk];
#pragma unroll
        for (int mt = 0; mt < 4; mt++)
#pragma unroll
            for (int nt = 0; nt < 4; nt++)
                acc[mt][nt] = __builtin_amdgcn_mfma_f32_16x16x32_bf16(af[mt], bv[nt], acc[mt][nt], 0, 0, 0);
    }
#pragma unroll
    for (int mt = 0; mt < 4; mt++)
#pragma unroll
        for (int nt = 0; nt < 4; nt++)
#pragma unroll
            for (int i = 0; i < 4; i++) {
                int row = mt * 16 + cr + i;
                int col = n0g + wave * 64 + nt * 16 + cc;
                Qord[(size_t)(e0 + row) * 512 + col] = (bf16)acc[mt][nt][i];
            }
}

// ---------------------------------------------------------------------------
// Fused edge update, restructured:
//  - A-tile (relu(SAB[src] ⊕ SAB[dst])) preloaded ONCE into LDS
//  - MFMA B-operands (em2W/eu1W/eu2W, 128 KB total, hot in L1/L2 across all
//    1024 blocks) read DIRECTLY from global → zero barriers inside K-loops
//  - LDS aliased: Afull (stage 1) overlaps med+t2s (stages 1-3) → 42 KB
//    → 3 blocks/CU (was 57 KB → 2 blocks/CU). Barriers: 36 → 4 per block.
// ---------------------------------------------------------------------------
__global__ __launch_bounds__(256) void k_edge(
    const float* __restrict__ SAB,
    const bf16* __restrict__ em2W, const float* __restrict__ em2b,
    const bf16* __restrict__ eu1W, const float* __restrict__ eu1b,
    const bf16* __restrict__ eu2W, const float* __restrict__ eu2b,
    const int* __restrict__ src, const int* __restrict__ dst,
    const int* __restrict__ pos,
    bf16* __restrict__ eaord, float* __restrict__ ea_out_f)
{
    __shared__ char smem[43008];
    bf16 (*Afull)[264] = (bf16 (*)[264])smem;            // 64x264 = 33792 B (stage 1 K-loop only)
    bf16 (*med)[200]   = (bf16 (*)[200])smem;            // 64x200 = 25600 B (stage 1 epi .. stage 2)
    bf16 (*t2s)[136]   = (bf16 (*)[136])(smem + 25600);  // 64x136 = 17408 B (stage 2 epi .. stage 3)

    const int e0 = blockIdx.x * 64;
    const int tid = threadIdx.x, wave = tid >> 6, lane = tid & 63;
    const int fr = lane & 15, fk = (lane >> 4) * 8;
    const int cc = lane & 15, cr = (lane >> 4) * 4;
    const floatx4 z4 = {0.f, 0.f, 0.f, 0.f};

    // ---------- preload A = relu(SAB[sI][c] + SAB[dI][256+c]) : 64x256 ----------
    {
        const int r = tid >> 2, cb = (tid & 3) * 64;
        const int sI = src[e0 + r], dI = dst[e0 + r];
        const float* ps = SAB + (size_t)sI * 512 + cb;
        const float* pd = SAB + (size_t)dI * 512 + 256 + cb;
#pragma unroll
        for (int j = 0; j < 8; j++) {
            float4 a = *(const float4*)(ps + j * 8);
            float4 b = *(const float4*)(ps + j * 8 + 4);
            float4 c = *(const float4*)(pd + j * 8);
            float4 d = *(const float4*)(pd + j * 8 + 4);
            bf16 t[8];
            t[0] = (bf16)fmaxf(a.x + c.x, 0.f); t[1] = (bf16)fmaxf(a.y + c.y, 0.f);
            t[2] = (bf16)fmaxf(a.z + c.z, 0.f); t[3] = (bf16)fmaxf(a.w + c.w, 0.f);
            t[4] = (bf16)fmaxf(b.x + d.x, 0.f); t[5] = (bf16)fmaxf(b.y + d.y, 0.f);
            t[6] = (bf16)fmaxf(b.z + d.z, 0.f); t[7] = (bf16)fmaxf(b.w + d.w, 0.f);
            *(bf16x8*)&Afull[r][cb + j * 8] = *(bf16x8*)t;
        }
    }
    __syncthreads();

    // ---------- stage 1: m_ed = relu(A @ em2W^T + em2b)  [64x128, K=256] ----------
    const int wm1 = (wave & 1) * 32, wn1 = (wave >> 1) * 64;
    floatx4 acc1[2][4];
#pragma unroll
    for (int mt = 0; mt < 2; mt++)
#pragma unroll
        for (int nt = 0; nt < 4; nt++) acc1[mt][nt] = z4;

    for (int k0 = 0; k0 < 256; k0 += 32) {
        bf16x8 af[2], bv[4];
        af[0] = *(const bf16x8*)&Afull[wm1 + fr][k0 + fk];
        af[1] = *(const bf16x8*)&Afull[wm1 + 16 + fr][k0 + fk];
#pragma unroll
        for (int nt = 0; nt < 4; nt++)
            bv[nt] = *(const bf16x8*)(em2W + (size_t)(wn1 + nt * 16 + fr) * 256 + k0 + fk);
#pragma unroll
        for (int mt = 0; mt < 2; mt++)
#pragma unroll
            for (int nt = 0; nt < 4; nt++)
                acc1[mt][nt] = __builtin_amdgcn_mfma_f32_16x16x32_bf16(af[mt], bv[nt], acc1[mt][nt], 0, 0, 0);
    }
    __syncthreads();   // Afull dead; safe to overwrite with med

#pragma unroll
    for (int mt = 0; mt < 2; mt++)
#pragma unroll
        for (int nt = 0; nt < 4; nt++)
#pragma unroll
            for (int i = 0; i < 4; i++) {
                int row = wm1 + mt * 16 + cr + i;
                int col = wn1 + nt * 16 + cc;
                med[row][col] = (bf16)fmaxf(acc1[mt][nt][i] + em2b[col], 0.f);
            }
    // append ea tile (CSR-ordered rows via pos)
    {
        int r = tid >> 2, c0 = (tid & 3) * 16;
        int pr = pos[e0 + r];
        *(bf16x8*)&med[r][128 + c0]     = *(const bf16x8*)(eaord + (size_t)pr * 64 + c0);
        *(bf16x8*)&med[r][128 + c0 + 8] = *(const bf16x8*)(eaord + (size_t)pr * 64 + c0 + 8);
    }
    __syncthreads();

    // ---------- stage 2: t2 = relu([m_ed|ea] @ eu1W^T + eu1b)  [64x128, K=192] ----------
    floatx4 acc2[2][4];
#pragma unroll
    for (int mt = 0; mt < 2; mt++)
#pragma unroll
        for (int nt = 0; nt < 4; nt++) acc2[mt][nt] = z4;

    for (int k0 = 0; k0 < 192; k0 += 32) {
        bf16x8 af[2], bv[4];
        af[0] = *(const bf16x8*)&med[wm1 + fr][k0 + fk];
        af[1] = *(const bf16x8*)&med[wm1 + 16 + fr][k0 + fk];
#pragma unroll
        for (int nt = 0; nt < 4; nt++)
            bv[nt] = *(const bf16x8*)(eu1W + (size_t)(wn1 + nt * 16 + fr) * 192 + k0 + fk);
#pragma unroll
        for (int mt = 0; mt < 2; mt++)
#pragma unroll
            for (int nt = 0; nt < 4; nt++)
                acc2[mt][nt] = __builtin_amdgcn_mfma_f32_16x16x32_bf16(af[mt], bv[nt], acc2[mt][nt], 0, 0, 0);
    }
    // t2s region is disjoint from med — no barrier needed before these writes
#pragma unroll
    for (int mt = 0; mt < 2; mt++)
#pragma unroll
        for (int nt = 0; nt < 4; nt++)
#pragma unroll
            for (int i = 0; i < 4; i++) {
                int row = wm1 + mt * 16 + cr + i;
                int col = wn1 + nt * 16 + cc;
                t2s[row][col] = (bf16)fmaxf(acc2[mt][nt][i] + eu1b[col], 0.f);
            }
    __syncthreads();

    // ---------- stage 3: ea' = t2 @ eu2W^T + eu2b  [64x64, K=128] ----------
    const int wm3 = (wave & 1) * 32, wn3 = (wave >> 1) * 32;
    floatx4 acc3[2][2];
#pragma unroll
    for (int mt = 0; mt < 2; mt++)
#pragma unroll
        for (int nt = 0; nt < 2; nt++) acc3[mt][nt] = z4;

    for (int k0 = 0; k0 < 128; k0 += 32) {
        bf16x8 af[2], bv[2];
        af[0] = *(const bf16x8*)&t2s[wm3 + fr][k0 + fk];
        af[1] = *(const bf16x8*)&t2s[wm3 + 16 + fr][k0 + fk];
#pragma unroll
        for (int nt = 0; nt < 2; nt++)
            bv[nt] = *(const bf16x8*)(eu2W + (size_t)(wn3 + nt * 16 + fr) * 128 + k0 + fk);
#pragma unroll
        for (int mt = 0; mt < 2; mt++)
#pragma unroll
            for (int nt = 0; nt < 2; nt++)
                acc3[mt][nt] = __builtin_amdgcn_mfma_f32_16x16x32_bf16(af[mt], bv[nt], acc3[mt][nt], 0, 0, 0);
    }
#pragma unroll
    for (int mt = 0; mt < 2; mt++)
#pragma unroll
        for (int nt = 0; nt < 2; nt++)
#pragma unroll
            for (int i = 0; i < 4; i++) {
                int row = wm3 + mt * 16 + cr + i;
                int col = wn3 + nt * 16 + cc;
                float v = acc3[mt][nt][i] + eu2b[col];
                int e = e0 + row;
                eaord[(size_t)pos[e] * 64 + col] = (bf16)v;
                if (ea_out_f) ea_out_f[(size_t)e * 64 + col] = v;  // final layer only
            }
}

// ---------------------------------------------------------------------------
// Post-MLP per-tower MFMA GEMM — now consumes bf16 agg buffers (identical
// rounding point; removes 8 scalar f32 loads+cvt per thread per k-step)
// ---------------------------------------------------------------------------
__global__ __launch_bounds__(256) void k_postg(
    const bf16* __restrict__ xin, const bf16* __restrict__ aggX,
    const bf16* __restrict__ aggS, const bf16* __restrict__ aggM,
    const bf16* __restrict__ qWbf, const float* __restrict__ qb,
    bf16* __restrict__ ybf)
{
    __shared__ bf16 As[64][40];
    __shared__ bf16 Ws[32][40];
    const int n0 = blockIdx.x * 64, t = blockIdx.y;
    const int tid = threadIdx.x, wave = tid >> 6, lane = tid & 63;
    const int lrow = tid >> 2, lcol = (tid & 3) * 8;
    const int fr = lane & 15, fk = (lane >> 4) * 8;
    floatx4 acc0 = {0,0,0,0}, acc1 = {0,0,0,0};

    for (int k0 = 0; k0 < 512; k0 += 32) {
        int n = n0 + lrow;
        int c0 = k0 + lcol;
        const bf16* srcp;
        if (c0 < 128)      srcp = xin  + (size_t)n * 128 + c0;
        else if (c0 < 256) srcp = aggX + (size_t)n * 512 + t * 128 + (c0 - 128);
        else if (c0 < 384) srcp = aggS + (size_t)n * 512 + t * 128 + (c0 - 256);
        else               srcp = aggM + (size_t)n * 512 + t * 128 + (c0 - 384);
        bf16x8 a8 = *(const bf16x8*)srcp;
        bf16 w8[8];
        if (tid < 128) {
            int wr = tid >> 2, wc = (tid & 3) * 8;
            *(bf16x8*)w8 = *(const bf16x8*)(qWbf + (size_t)(t * 32 + wr) * 512 + k0 + wc);
        }
        __syncthreads();
        *(bf16x8*)&As[lrow][lcol] = a8;
        if (tid < 128) {
            int wr = tid >> 2, wc = (tid & 3) * 8;
            *(bf16x8*)&Ws[wr][wc] = *(bf16x8*)w8;
        }
        __syncthreads();
        bf16x8 a  = *(const bf16x8*)&As[wave * 16 + fr][fk];
        bf16x8 b0 = *(const bf16x8*)&Ws[fr][fk];
        bf16x8 b1 = *(const bf16x8*)&Ws[16 + fr][fk];
        acc0 = __builtin_amdgcn_mfma_f32_16x16x32_bf16(a, b0, acc0, 0, 0, 0);
        acc1 = __builtin_amdgcn_mfma_f32_16x16x32_bf16(a, b1, acc1, 0, 0, 0);
    }
    const int cc = lane & 15, cr = (lane >> 4) * 4;
#pragma unroll
    for (int i = 0; i < 4; i++) {
        int gn = n0 + wave * 16 + cr + i;
        ybf[(size_t)gn * 128 + t * 32 + cc]      = (bf16)(acc0[i] + qb[t * 32 + cc]);
        ybf[(size_t)gn * 128 + t * 32 + 16 + cc] = (bf16)(acc1[i] + qb[t * 32 + 16 + cc]);
    }
}

// ---------------------------------------------------------------------------
// Fold edge-encoder into pre-MLP; writes zero-extended bias [1024].
// ---------------------------------------------------------------------------
__global__ __launch_bounds__(64) void k_wcomb(
    const float* __restrict__ preW, const float* __restrict__ encW,
    const float* __restrict__ encb, const float* __restrict__ preb,
    bf16* __restrict__ wcomb, float* __restrict__ bcombext)
{
    int tf = blockIdx.x, d = threadIdx.x;
    __shared__ float pw[128];
    __shared__ float red[64];
    const float* pr = preW + (size_t)tf * 384 + 256;
    pw[d]      = pr[d];
    pw[d + 64] = pr[d + 64];
    __syncthreads();
    float acc = 0.f;
    for (int h = 0; h < 128; h++) acc += pw[h] * encW[h * 64 + d];
    wcomb[tf * 64 + d] = (bf16)acc;
    float b = pw[d] * encb[d] + pw[d + 64] * encb[d + 64];
    red[d] = b;
    __syncthreads();
    for (int s = 32; s > 0; s >>= 1) { if (d < s) red[d] += red[d + s]; __syncthreads(); }
    if (d == 0) {
        bcombext[tf] = red[0] + preb[tf];
        bcombext[512 + tf] = 0.f;
    }
}

// ---------------- weight repacks (once per launch) --------------------------
__global__ void k_rep_node(const bf16* __restrict__ preWbf, bf16* __restrict__ Wnode)
{
    int i = blockIdx.x * 256 + threadIdx.x;   // 3*1024*128
    int l = i >> 17, rem = i & 131071;
    int r = rem >> 7, c = rem & 127;
    bf16 v = (r < 512) ? preWbf[(size_t)l * 196608 + (size_t)r * 384 + c]
                       : preWbf[(size_t)l * 196608 + (size_t)(r - 512) * 384 + 128 + c];
    Wnode[i] = v;
}

__global__ void k_rep_em1(const bf16* __restrict__ em1Wbf, bf16* __restrict__ Wem1)
{
    int i = blockIdx.x * 256 + threadIdx.x;   // 512*128
    int r = i >> 7, c = i & 127;
    bf16 v = (r < 256) ? em1Wbf[(size_t)r * 256 + c]
                       : em1Wbf[(size_t)(r - 256) * 256 + 128 + c];
    Wem1[i] = v;
}

__global__ void k_ext_em1b(const float* __restrict__ em1b, float* __restrict__ ext)
{
    int i = blockIdx.x * 256 + threadIdx.x;   // 512
    ext[i] = (i < 256) ? em1b[i] : 0.f;
}

// ----------------------- CSR build -----------------------------------------
__global__ void k_count(const int* __restrict__ dst, int* __restrict__ counts)
{
    int e = blockIdx.x * 256 + threadIdx.x;
    atomicAdd(&counts[dst[e]], 1);
}

__global__ __launch_bounds__(1024) void k_scan(
    const int* __restrict__ counts, int* __restrict__ offs, int* __restrict__ cursor)
{
    __shared__ int ls[1024];
    int tid = threadIdx.x, base = tid * 4;
    int c0 = counts[base], c1 = counts[base + 1], c2 = counts[base + 2], c3 = counts[base + 3];
    ls[tid] = c0 + c1 + c2 + c3;
    __syncthreads();
    for (int d = 1; d < 1024; d <<= 1) {
        int v = (tid >= d) ? ls[tid - d] : 0;
        __syncthreads();
        ls[tid] += v;
        __syncthreads();
    }
    int r = tid ? ls[tid - 1] : 0;
    offs[base] = r;     cursor[base] = r;     r += c0;
    offs[base + 1] = r; cursor[base + 1] = r; r += c1;
    offs[base + 2] = r; cursor[base + 2] = r; r += c2;
    offs[base + 3] = r; cursor[base + 3] = r; r += c3;
    if (tid == 1023) offs[4096] = r;
}

__global__ void k_fill(const int* __restrict__ dst, const int* __restrict__ srcW,
                       int* __restrict__ cursor, int* __restrict__ pos,
                       int* __restrict__ srcord)
{
    int e = blockIdx.x * 256 + threadIdx.x;
    int p = atomicAdd(&cursor[dst[e]], 1);
    pos[e] = p;
    srcord[p] = srcW[e];
}

// ---------------------------------------------------------------------------
// Single-pass aggregation; outputs now bf16 (postg casts to bf16 anyway —
// identical rounding point, halves agg-buffer HBM traffic both directions)
// ---------------------------------------------------------------------------
__global__ __launch_bounds__(128) void k_agg(
    const float* __restrict__ PdPs, const bf16* __restrict__ Qord,
    const int* __restrict__ srcord, const int* __restrict__ offs,
    bf16* __restrict__ aggX, bf16* __restrict__ aggS, bf16* __restrict__ aggM)
{
    int n = blockIdx.x, tid = threadIdx.x;
    int c = tid * 4;
    float4 pd = *(const float4*)(PdPs + (size_t)n * 1024 + c);
    float s0 = 0, s1 = 0, s2 = 0, s3 = 0;
    float q0 = 0, q1 = 0, q2 = 0, q3 = 0;
    float x0 = -3e38f, x1 = -3e38f, x2 = -3e38f, x3 = -3e38f;
    int beg = offs[n], end = offs[n + 1];
    for (int i = beg; i < end; i++) {
        int sn = srcord[i];
        float4 ps = *(const float4*)(PdPs + (size_t)sn * 1024 + 512 + c);
        bf16x4 qv = *(const bf16x4*)(Qord + (size_t)i * 512 + c);
        float m0 = pd.x + ps.x + (float)qv[0];
        float m1 = pd.y + ps.y + (float)qv[1];
        float m2 = pd.z + ps.z + (float)qv[2];
        float m3 = pd.w + ps.w + (float)qv[3];
        s0 += m0; s1 += m1; s2 += m2; s3 += m3;
        q0 += m0 * m0; q1 += m1 * m1; q2 += m2 * m2; q3 += m3 * m3;
        x0 = fmaxf(x0, m0); x1 = fmaxf(x1, m1); x2 = fmaxf(x2, m2); x3 = fmaxf(x3, m3);
    }
    int cnt = end - beg;
    float inv = 1.f / fmaxf((float)cnt, 1.f);
    float me0 = s0 * inv, me1 = s1 * inv, me2 = s2 * inv, me3 = s3 * inv;
    float v0 = fmaxf(q0 * inv - me0 * me0, 0.f);
    float v1 = fmaxf(q1 * inv - me1 * me1, 0.f);
    float v2 = fmaxf(q2 * inv - me2 * me2, 0.f);
    float v3 = fmaxf(q3 * inv - me3 * me3, 0.f);
    size_t o = (size_t)n * 512 + c;
    bf16x4 mx, st, me;
    mx[0] = (bf16)(cnt > 0 ? x0 : 0.f); mx[1] = (bf16)(cnt > 0 ? x1 : 0.f);
    mx[2] = (bf16)(cnt > 0 ? x2 : 0.f); mx[3] = (bf16)(cnt > 0 ? x3 : 0.f);
    st[0] = (bf16)sqrtf(v0 + 1e-5f); st[1] = (bf16)sqrtf(v1 + 1e-5f);
    st[2] = (bf16)sqrtf(v2 + 1e-5f); st[3] = (bf16)sqrtf(v3 + 1e-5f);
    me[0] = (bf16)me0; me[1] = (bf16)me1; me[2] = (bf16)me2; me[3] = (bf16)me3;
    *(bf16x4*)(aggX + o) = mx;
    *(bf16x4*)(aggS + o) = st;
    *(bf16x4*)(aggM + o) = me;
}

// --------------------------- GRU elementwise --------------------------------
// fo != nullptr on the final layer: writes out directly into d_out (both the
// leading and trailing out-copies), eliminating k_writeout entirely.
__global__ void k_gru(const float* __restrict__ gi, const float* __restrict__ gh,
                      float* __restrict__ hst, bf16* __restrict__ ob,
                      float* __restrict__ fo)
{
    int i = blockIdx.x * 256 + threadIdx.x;
    int k = i & 127;
    size_t b = (size_t)(i >> 7) * 384;
    float ir = gi[b + k],       hr = gh[b + k];
    float iz = gi[b + 128 + k], hz = gh[b + 128 + k];
    float ic = gi[b + 256 + k], hc = gh[b + 256 + k];
    float r = 1.f / (1.f + __expf(-(ir + hr)));
    float z = 1.f / (1.f + __expf(-(iz + hz)));
    float c = tanhf(ic + r * hc);
    float h = hst[i];
    float hn = (1.f - z) * c + z * h;
    hst[i] = hn;
    ob[i] = (bf16)hn;
    if (fo) { fo[i] = hn; fo[4718592 + i] = hn; }
}

__global__ void k_sentinel(float* __restrict__ o, float v)
{
    int i = blockIdx.x * 256 + threadIdx.x;
    o[i] = v;
}

// ===========================================================================
extern "C" void kernel_launch(void* const* d_in, const int* in_sizes, int n_in,
                              void* d_out, int out_size, void* d_ws, size_t ws_size,
                              hipStream_t stream)
{
    static const int exp_sizes[23] = {
        524288, 4194304, 131072, 24576, 384, 589824, 1536, 196608, 384,
        49152, 384, 49152, 49152, 384, 384, 65536, 256, 32768, 128,
        24576, 128, 8192, 64 };
    if (n_in != 23) { k_sentinel<<<2048, 256, 0, stream>>>((float*)d_out, 200.f); return; }
    for (int i = 0; i < 23; i++)
        if (in_sizes[i] != exp_sizes[i]) {
            k_sentinel<<<2048, 256, 0, stream>>>((float*)d_out, 60.f + 4.f * i);
            return;
        }
    if (out_size != 5242880) { k_sentinel<<<2048, 256, 0, stream>>>((float*)d_out, 52.f); return; }

    const int* eidx = (const int*)d_in[2];

    char* w = (char*)d_ws;
    size_t off = 0;
    auto alloc = [&](size_t bytes) -> char* {
        char* p = w + off;
        off = (off + bytes + 255) & ~(size_t)255;
        return p;
    };
    int*   dflag   = (int*)  alloc(256);
    int*   iflag   = (int*)  alloc(256);
    int*   srcW    = (int*)  alloc((size_t)EE * 4);
    int*   dstW    = (int*)  alloc((size_t)EE * 4);
    int*   pos     = (int*)  alloc((size_t)EE * 4);
    int*   srcord  = (int*)  alloc((size_t)EE * 4);
    float* out_f32 = (float*)alloc((size_t)NN * HH * 4);
    bf16*  out_bf  = (bf16*) alloc((size_t)NN * HH * 2);
    bf16*  m_bf    = (bf16*) alloc((size_t)NN * HH * 2);
    bf16*  ybf     = (bf16*) alloc((size_t)NN * HH * 2);
    bf16*  eaord   = (bf16*) alloc((size_t)EE * EDD * 2);
    bf16*  wcombBf = (bf16*) alloc((size_t)THD * EDD * 2);
    float* bcombx  = (float*)alloc((size_t)1024 * 4);
    int*   counts  = (int*)  alloc((size_t)NN * 4);
    int*   offs    = (int*)  alloc((size_t)(NN + 1) * 4);
    int*   cursor  = (int*)  alloc((size_t)NN * 4);
    float* PdPs    = (float*)alloc((size_t)NN * 1024 * 4);
    bf16*  aggX    = (bf16*) alloc((size_t)NN * THD * 2);
    bf16*  aggS    = (bf16*) alloc((size_t)NN * THD * 2);
    bf16*  aggM    = (bf16*) alloc((size_t)NN * THD * 2);
    float* encWc  = (float*)alloc((size_t)24576 * 4);
    float* encbc  = (float*)alloc((size_t)384 * 4);
    float* preWc  = (float*)alloc((size_t)589824 * 4);
    float* prebc  = (float*)alloc((size_t)1536 * 4);
    float* postbc = (float*)alloc((size_t)384 * 4);
    float* linbc  = (float*)alloc((size_t)384 * 4);
    float* bihc   = (float*)alloc((size_t)384 * 4);
    float* bhhc   = (float*)alloc((size_t)384 * 4);
    float* em1bc  = (float*)alloc((size_t)256 * 4);
    float* em1ext = (float*)alloc((size_t)512 * 4);
    float* em2bc  = (float*)alloc((size_t)128 * 4);
    float* eu1bc  = (float*)alloc((size_t)128 * 4);
    float* eu2bc  = (float*)alloc((size_t)64 * 4);
    bf16* preWbf = (bf16*)alloc((size_t)589824 * 2);
    bf16* WnodeBf= (bf16*)alloc((size_t)3 * 131072 * 2);
    bf16* postWbf= (bf16*)alloc((size_t)196608 * 2);
    bf16* linWbf = (bf16*)alloc((size_t)49152 * 2);
    bf16* WihBf  = (bf16*)alloc((size_t)49152 * 2);
    bf16* WhhBf  = (bf16*)alloc((size_t)49152 * 2);
    bf16* em1Wbf = (bf16*)alloc((size_t)65536 * 2);
    bf16* Wem1Bf = (bf16*)alloc((size_t)65536 * 2);
    bf16* em2Wbf = (bf16*)alloc((size_t)32768 * 2);
    bf16* eu1Wbf = (bf16*)alloc((size_t)24576 * 2);
    bf16* eu2Wbf = (bf16*)alloc((size_t)8192 * 2);
    // phase-shared region: Q_ord (PNA) / gi,gh (GRU) / SAB (edge)
    char* region = alloc((size_t)EE * 512 * 2);     // 67.1 MB
    bf16*  Qord = (bf16*) (region);
    float* gi   = (float*)(region);
    float* gh   = (float*)(region + 6291456);
    float* SAB  = (float*)(region);                 // [N,512] f32

    if (ws_size < off) { k_sentinel<<<2048, 256, 0, stream>>>((float*)d_out, 44.f); return; }

    // ---- index canonicalize + CSR ----
    k_detidx<<<1, 64, 0, stream>>>(eidx, iflag);
    k_extidx<<<EE / 256, 256, 0, stream>>>(eidx, srcW, dstW, iflag);
    hipMemsetAsync(counts, 0, NN * 4, stream);
    k_count<<<EE / 256, 256, 0, stream>>>(dstW, counts);
    k_scan<<<1, 1024, 0, stream>>>(counts, offs, cursor);
    k_fill<<<EE / 256, 256, 0, stream>>>(dstW, srcW, cursor, pos, srcord);

    // ---- float canonicalize ----
    k_detect<<<1, 64, 0, stream>>>(d_in[1], dflag);
    auto CF = [&](int idx, float* dst, int n) {
        k_canon_f<<<(n + 255) / 256, 256, 0, stream>>>(d_in[idx], dst, n, dflag);
    };
    auto CB = [&](int idx, bf16* dst, int n) {
        k_canon_b<<<(n + 255) / 256, 256, 0, stream>>>(d_in[idx], dst, n, dflag);
    };
    k_canon_fb<<<(NN * HH + 255) / 256, 256, 0, stream>>>(d_in[0], out_f32, out_bf, NN * HH, dflag);
    k_canon_ea<<<(EE * EDD + 255) / 256, 256, 0, stream>>>(d_in[1], eaord, pos, dflag);
    k_canon_fb<<<(589824 + 255) / 256, 256, 0, stream>>>(d_in[5], preWc, preWbf, 589824, dflag);
    CF(3, encWc, 24576);   CF(4, encbc, 384);   CF(6, prebc, 1536);
    CF(8, postbc, 384);    CF(10, linbc, 384);  CF(13, bihc, 384);  CF(14, bhhc, 384);
    CF(16, em1bc, 256);    CF(18, em2bc, 128);  CF(20, eu1bc, 128); CF(22, eu2bc, 64);
    CB(7, postWbf, 196608); CB(9, linWbf, 49152);
    CB(11, WihBf, 49152);   CB(12, WhhBf, 49152);
    CB(15, em1Wbf, 65536);  CB(17, em2Wbf, 32768);
    CB(19, eu1Wbf, 24576);  CB(21, eu2Wbf, 8192);
    // repacks
    k_rep_node<<<(3 * 131072) / 256, 256, 0, stream>>>(preWbf, WnodeBf);
    k_rep_em1<<<65536 / 256, 256, 0, stream>>>(em1Wbf, Wem1Bf);
    k_ext_em1b<<<2, 256, 0, stream>>>(em1bc, em1ext);

    auto GEMM = [&](const bf16* A, int lda, const bf16* Wm, int ldw, const float* bias,
                    void* C, int ldc, int M, int Nout, int K, bool relu, int om) {
        dim3 grid(M / 64, Nout / 64);
        if (relu) {
            if (om) k_mgemm<true, 1><<<grid, 256, 0, stream>>>(A, lda, Wm, ldw, bias, C, ldc, K);
            else    k_mgemm<true, 0><<<grid, 256, 0, stream>>>(A, lda, Wm, ldw, bias, C, ldc, K);
        } else {
            if (om) k_mgemm<false, 1><<<grid, 256, 0, stream>>>(A, lda, Wm, ldw, bias, C, ldc, K);
            else    k_mgemm<false, 0><<<grid, 256, 0, stream>>>(A, lda, Wm, ldw, bias, C, ldc, K);
        }
    };

    for (int l = 0; l < 3; l++) {
        const float* preW_l  = preWc  + (size_t)l * 196608;
        const float* encW_l  = encWc  + (size_t)l * 8192;
        const float* encb_l  = encbc  + (size_t)l * 128;
        const float* preb_l  = prebc  + (size_t)l * 512;
        const bf16*  Wnode_l = WnodeBf + (size_t)l * 131072;
        const bf16*  postW_l = postWbf + (size_t)l * 65536;
        const float* postb_l = postbc + (size_t)l * 128;
        const bf16*  linW_l  = linWbf + (size_t)l * 16384;
        const float* linb_l  = linbc  + (size_t)l * 128;
        const bool last = (l == 2);

        // ---- PNA ----
        k_wcomb<<<THD, 64, 0, stream>>>(preW_l, encW_l, encb_l, preb_l, wcombBf, bcombx);
        GEMM(out_bf, HH, Wnode_l, 128, bcombx, PdPs, 1024, NN, 1024, HH, false, 0);
        k_qgemm<<<dim3(EE / 64, 2), 256, 0, stream>>>(eaord, wcombBf, Qord);
        k_agg<<<NN, 128, 0, stream>>>(PdPs, Qord, srcord, offs, aggX, aggS, aggM);
        k_postg<<<dim3(NN / 64, 4), 256, 0, stream>>>(out_bf, aggX, aggS, aggM,
                                                      postW_l, postb_l, ybf);
        GEMM(ybf, HH, linW_l, HH, linb_l, m_bf, HH, NN, HH, HH, true, 1);
        // ---- GRU ----
        GEMM(m_bf,   HH, WihBf, HH, bihc, gi, 384, NN, 384, HH, false, 0);
        GEMM(out_bf, HH, WhhBf, HH, bhhc, gh, 384, NN, 384, HH, false, 0);
        k_gru<<<NN * HH / 256, 256, 0, stream>>>(gi, gh, out_f32, out_bf,
                                                 last ? (float*)d_out : (float*)nullptr);
        // ---- edge update (merged SAB + fused chain) ----
        GEMM(out_bf, HH, Wem1Bf, 128, em1ext, SAB, 512, NN, 512, HH, false, 0);
        k_edge<<<EE / 64, 256, 0, stream>>>(SAB, em2Wbf, em2bc, eu1Wbf, eu1bc,
                                            eu2Wbf, eu2bc, srcW, dstW, pos,
                                            eaord, last ? (float*)d_out + 524288 : (float*)nullptr);
    }
}

// Round 2
// 604.926 us; speedup vs baseline: 1.0687x; 1.0687x over previous
//
#include <hip/hip_runtime.h>
#include <hip/hip_bf16.h>
#include <math.h>

#define NN 4096
#define EE 65536
#define HH 128
#define EDD 64
#define THD 512

typedef __bf16 bf16;
typedef __bf16 bf16x8 __attribute__((ext_vector_type(8)));
typedef __bf16 bf16x4 __attribute__((ext_vector_type(4)));
typedef float  floatx4 __attribute__((ext_vector_type(4)));

// ---------------------------------------------------------------------------
// input dtype detects (proven: floats f32, edge_index int32; cheap insurance)
// ---------------------------------------------------------------------------
__global__ __launch_bounds__(64) void k_detect(const void* __restrict__ p,
                                               int* __restrict__ flag)
{
    const bf16* b = (const bf16*)p;
    int t = threadIdx.x;
    int bad = 0;
    for (int i = 0; i < 32; i++) {
        float v = (float)b[t * 32 + i];
        if (!(v == v) || fabsf(v) > 100.f) bad = 1;
    }
    unsigned long long m = __ballot(bad);
    if (t == 0) *flag = (m == 0ULL) ? 1 : 0;
}

__global__ void k_canon_f(const void* __restrict__ src, float* __restrict__ dst,
                          int n, const int* __restrict__ flag)
{
    int i = blockIdx.x * 256 + threadIdx.x;
    if (i >= n) return;
    dst[i] = (*flag) ? (float)((const bf16*)src)[i] : ((const float*)src)[i];
}

__global__ void k_canon_b(const void* __restrict__ src, bf16* __restrict__ dst,
                          int n, const int* __restrict__ flag)
{
    int i = blockIdx.x * 256 + threadIdx.x;
    if (i >= n) return;
    dst[i] = (*flag) ? ((const bf16*)src)[i] : (bf16)((const float*)src)[i];
}

__global__ void k_canon_fb(const void* __restrict__ src, float* __restrict__ dst,
                           bf16* __restrict__ dst2, int n, const int* __restrict__ flag)
{
    int i = blockIdx.x * 256 + threadIdx.x;
    if (i >= n) return;
    float v = (*flag) ? (float)((const bf16*)src)[i] : ((const float*)src)[i];
    dst[i] = v;
    dst2[i] = (bf16)v;
}

// ea canon: CSR-ordered bf16 only (f32 ea only needed as FINAL output,
// written directly to d_out by layer-3 k_edge)
__global__ void k_canon_ea(const void* __restrict__ src,
                           bf16* __restrict__ eaord, const int* __restrict__ pos,
                           const int* __restrict__ flag)
{
    int i = blockIdx.x * 256 + threadIdx.x;   // E*64
    int e = i >> 6, d = i & 63;
    float v = (*flag) ? (float)((const bf16*)src)[i] : ((const float*)src)[i];
    eaord[(size_t)pos[e] * 64 + d] = (bf16)v;
}

__global__ __launch_bounds__(64) void k_detidx(const int* __restrict__ p,
                                               int* __restrict__ iflag)
{
    int t = threadIdx.x;
    int bad = 0;
    for (int i = 0; i < 8; i++) {
        int k = t * 8 + i;
        int lo = p[2 * k], hi = p[2 * k + 1];
        if (hi != 0 || lo < 0 || lo >= NN) bad = 1;
    }
    unsigned long long m = __ballot(bad);
    if (t == 0) *iflag = (m == 0ULL) ? 1 : 0;
}

__global__ void k_extidx(const int* __restrict__ p, int* __restrict__ srcW,
                         int* __restrict__ dstW, const int* __restrict__ iflag)
{
    int e = blockIdx.x * 256 + threadIdx.x;
    int s, d;
    if (*iflag) { s = p[2 * e];  d = p[2 * EE + 2 * e]; }
    else        { s = p[e];      d = p[EE + e]; }
    srcW[e] = min(max(s, 0), NN - 1);
    dstW[e] = min(max(d, 0), NN - 1);
}

// ---------------------------------------------------------------------------
// MFMA bf16 GEMM (validated): C[M,Nout] = act(A @ W^T + bias)
// ---------------------------------------------------------------------------
template<bool RELU, int OM>
__global__ __launch_bounds__(256) void k_mgemm(
    const bf16* __restrict__ A, int lda,
    const bf16* __restrict__ W, int ldw, const float* __restrict__ bias,
    void* __restrict__ Cv, int ldc, int K)
{
    __shared__ bf16 As[64][40];
    __shared__ bf16 Ws[64][40];
    const int m0 = blockIdx.x * 64, n0 = blockIdx.y * 64;
    const int tid = threadIdx.x, wave = tid >> 6, lane = tid & 63;
    const int wm = (wave & 1) * 32, wn = (wave >> 1) * 32;
    const int lrow = tid >> 2, lcol = (tid & 3) * 8;
    const int fr = lane & 15, fk = (lane >> 4) * 8;
    floatx4 acc00 = {0,0,0,0}, acc01 = {0,0,0,0}, acc10 = {0,0,0,0}, acc11 = {0,0,0,0};

    for (int k0 = 0; k0 < K; k0 += 32) {
        bf16x8 av = *(const bf16x8*)(A + (size_t)(m0 + lrow) * lda + k0 + lcol);
        bf16x8 wv = *(const bf16x8*)(W + (size_t)(n0 + lrow) * ldw + k0 + lcol);
        __syncthreads();
        *(bf16x8*)&As[lrow][lcol] = av;
        *(bf16x8*)&Ws[lrow][lcol] = wv;
        __syncthreads();
        bf16x8 a0 = *(const bf16x8*)&As[wm + fr][fk];
        bf16x8 a1 = *(const bf16x8*)&As[wm + 16 + fr][fk];
        bf16x8 b0 = *(const bf16x8*)&Ws[wn + fr][fk];
        bf16x8 b1 = *(const bf16x8*)&Ws[wn + 16 + fr][fk];
        acc00 = __builtin_amdgcn_mfma_f32_16x16x32_bf16(a0, b0, acc00, 0, 0, 0);
        acc01 = __builtin_amdgcn_mfma_f32_16x16x32_bf16(a0, b1, acc01, 0, 0, 0);
        acc10 = __builtin_amdgcn_mfma_f32_16x16x32_bf16(a1, b0, acc10, 0, 0, 0);
        acc11 = __builtin_amdgcn_mfma_f32_16x16x32_bf16(a1, b1, acc11, 0, 0, 0);
    }
    const int cc = lane & 15, cr = (lane >> 4) * 4;
    float vb0 = bias ? bias[n0 + wn + cc] : 0.f;
    float vb1 = bias ? bias[n0 + wn + 16 + cc] : 0.f;
    floatx4 accs[2][2] = {{acc00, acc01}, {acc10, acc11}};
#pragma unroll
    for (int mt = 0; mt < 2; mt++)
#pragma unroll
        for (int nt = 0; nt < 2; nt++) {
            float vb = nt ? vb1 : vb0;
#pragma unroll
            for (int i = 0; i < 4; i++) {
                int gm = m0 + wm + mt * 16 + cr + i;
                int gn = n0 + wn + nt * 16 + cc;
                float v = accs[mt][nt][i] + vb;
                if (RELU) v = fmaxf(v, 0.f);
                if (OM == 1) ((bf16*)Cv)[(size_t)gm * ldc + gn] = (bf16)v;
                else         ((float*)Cv)[(size_t)gm * ldc + gn] = v;
            }
        }
}

// ---------------------------------------------------------------------------
// Q GEMM, wide tile: Q_ord[E,512] = eaord[E,64] @ wcomb[512,64]^T
// ---------------------------------------------------------------------------
__global__ __launch_bounds__(256) void k_qgemm(
    const bf16* __restrict__ eaord, const bf16* __restrict__ wcomb,
    bf16* __restrict__ Qord)
{
    __shared__ bf16 As[64][72];
    __shared__ bf16 Ws[256][72];
    const int e0 = blockIdx.x * 64, n0g = blockIdx.y * 256;
    const int tid = threadIdx.x, wave = tid >> 6, lane = tid & 63;
    const int fr = lane & 15, fk = (lane >> 4) * 8;
    const int cc = lane & 15, cr = (lane >> 4) * 4;

#pragma unroll
    for (int v = 0; v < 2; v++) {
        int lin = v * 2048 + tid * 8;
        int r = lin >> 6, c = lin & 63;
        *(bf16x8*)&As[r][c] = *(const bf16x8*)(eaord + (size_t)(e0 + r) * 64 + c);
    }
#pragma unroll
    for (int v = 0; v < 8; v++) {
        int lin = v * 2048 + tid * 8;
        int r = lin >> 6, c = lin & 63;
        *(bf16x8*)&Ws[r][c] = *(const bf16x8*)(wcomb + (size_t)(n0g + r) * 64 + c);
    }
    __syncthreads();

    floatx4 acc[4][4];
#pragma unroll
    for (int mt = 0; mt < 4; mt++)
#pragma unroll
        for (int nt = 0; nt < 4; nt++) acc[mt][nt] = (floatx4){0,0,0,0};

#pragma unroll
    for (int kk = 0; kk < 64; kk += 32) {
        bf16x8 af[4], bv[4];
#pragma unroll
        for (int mt = 0; mt < 4; mt++) af[mt] = *(const bf16x8*)&As[mt * 16 + fr][kk + fk];
#pragma unroll
        for (int nt = 0; nt < 4; nt++) bv[nt] = *(const bf16x8*)&Ws[wave * 64 + nt * 16 + fr][kk + fk];
#pragma unroll
        for (int mt = 0; mt < 4; mt++)
#pragma unroll
            for (int nt = 0; nt < 4; nt++)
                acc[mt][nt] = __builtin_amdgcn_mfma_f32_16x16x32_bf16(af[mt], bv[nt], acc[mt][nt], 0, 0, 0);
    }
#pragma unroll
    for (int mt = 0; mt < 4; mt++)
#pragma unroll
        for (int nt = 0; nt < 4; nt++)
#pragma unroll
            for (int i = 0; i < 4; i++) {
                int row = mt * 16 + cr + i;
                int col = n0g + wave * 64 + nt * 16 + cc;
                Qord[(size_t)(e0 + row) * 512 + col] = (bf16)acc[mt][nt][i];
            }
}

// ---------------------------------------------------------------------------
// Fused edge update, hybrid of R0 (validated LDS weight staging — MFMA
// operands never depend on in-flight global loads) and R1 (A-tile preloaded
// once, vectorized; LDS aliasing).
//   LDS: Ws 10.2K + union(Afull 33.8K | med 25.6K) + t2s 17.4K = 52 KB
//        → 3 blocks/CU (R0 was 57 KB → 2 blocks/CU)
// ---------------------------------------------------------------------------
__global__ __launch_bounds__(256) void k_edge(
    const float* __restrict__ SAB,
    const bf16* __restrict__ em2W, const float* __restrict__ em2b,
    const bf16* __restrict__ eu1W, const float* __restrict__ eu1b,
    const bf16* __restrict__ eu2W, const float* __restrict__ eu2b,
    const int* __restrict__ src, const int* __restrict__ dst,
    const int* __restrict__ pos,
    bf16* __restrict__ eaord, float* __restrict__ ea_out_f)
{
    __shared__ char smem[53248];
    bf16 (*Ws)[40]     = (bf16 (*)[40])smem;                  // 128x40 = 10240 B
    bf16 (*Afull)[264] = (bf16 (*)[264])(smem + 10240);       // 64x264 = 33792 B (stage 1)
    bf16 (*med)[200]   = (bf16 (*)[200])(smem + 10240);       // 64x200 = 25600 B (aliases Afull)
    bf16 (*t2s)[136]   = (bf16 (*)[136])(smem + 35840);       // 64x136 = 17408 B

    const int e0 = blockIdx.x * 64;
    const int tid = threadIdx.x, wave = tid >> 6, lane = tid & 63;
    const int fr = lane & 15, fk = (lane >> 4) * 8;
    const int cc = lane & 15, cr = (lane >> 4) * 4;
    const floatx4 z4 = {0.f, 0.f, 0.f, 0.f};

    // ---------- preload A = relu(SAB[sI][c] + SAB[dI][256+c]) : 64x256 ----------
    {
        const int r = tid >> 2, cb = (tid & 3) * 64;
        const int sI = src[e0 + r], dI = dst[e0 + r];
        const float* ps = SAB + (size_t)sI * 512 + cb;
        const float* pq = SAB + (size_t)dI * 512 + 256 + cb;
#pragma unroll
        for (int j = 0; j < 8; j++) {
            float4 a = *(const float4*)(ps + j * 8);
            float4 b = *(const float4*)(ps + j * 8 + 4);
            float4 c = *(const float4*)(pq + j * 8);
            float4 d = *(const float4*)(pq + j * 8 + 4);
            bf16 t[8];
            t[0] = (bf16)fmaxf(a.x + c.x, 0.f); t[1] = (bf16)fmaxf(a.y + c.y, 0.f);
            t[2] = (bf16)fmaxf(a.z + c.z, 0.f); t[3] = (bf16)fmaxf(a.w + c.w, 0.f);
            t[4] = (bf16)fmaxf(b.x + d.x, 0.f); t[5] = (bf16)fmaxf(b.y + d.y, 0.f);
            t[6] = (bf16)fmaxf(b.z + d.z, 0.f); t[7] = (bf16)fmaxf(b.w + d.w, 0.f);
            *(bf16x8*)&Afull[r][cb + j * 8] = *(bf16x8*)t;
        }
    }
    __syncthreads();

    // ---------- stage 1: m_ed = relu(A @ em2W^T + em2b)  [64x128, K=256] ----------
    const int wm1 = (wave & 1) * 32, wn1 = (wave >> 1) * 64;
    floatx4 acc1[2][4];
#pragma unroll
    for (int mt = 0; mt < 2; mt++)
#pragma unroll
        for (int nt = 0; nt < 4; nt++) acc1[mt][nt] = z4;

    for (int k0 = 0; k0 < 256; k0 += 32) {
        int wr = tid & 127, wc = (tid >> 7) * 16;
        bf16x8 w0 = *(const bf16x8*)(em2W + (size_t)wr * 256 + k0 + wc);
        bf16x8 w1 = *(const bf16x8*)(em2W + (size_t)wr * 256 + k0 + wc + 8);
        __syncthreads();
        *(bf16x8*)&Ws[wr][wc]     = w0;
        *(bf16x8*)&Ws[wr][wc + 8] = w1;
        __syncthreads();
        bf16x8 af[2], bv[4];
        af[0] = *(const bf16x8*)&Afull[wm1 + fr][k0 + fk];
        af[1] = *(const bf16x8*)&Afull[wm1 + 16 + fr][k0 + fk];
#pragma unroll
        for (int nt = 0; nt < 4; nt++) bv[nt] = *(const bf16x8*)&Ws[wn1 + nt * 16 + fr][fk];
#pragma unroll
        for (int mt = 0; mt < 2; mt++)
#pragma unroll
            for (int nt = 0; nt < 4; nt++)
                acc1[mt][nt] = __builtin_amdgcn_mfma_f32_16x16x32_bf16(af[mt], bv[nt], acc1[mt][nt], 0, 0, 0);
    }
    __syncthreads();   // all waves done reading Afull → safe to overwrite with med

#pragma unroll
    for (int mt = 0; mt < 2; mt++)
#pragma unroll
        for (int nt = 0; nt < 4; nt++)
#pragma unroll
            for (int i = 0; i < 4; i++) {
                int row = wm1 + mt * 16 + cr + i;
                int col = wn1 + nt * 16 + cc;
                med[row][col] = (bf16)fmaxf(acc1[mt][nt][i] + em2b[col], 0.f);
            }
    // append ea tile (CSR-ordered rows via pos)
    {
        int r = tid >> 2, c0 = (tid & 3) * 16;
        int pr = pos[e0 + r];
        *(bf16x8*)&med[r][128 + c0]     = *(const bf16x8*)(eaord + (size_t)pr * 64 + c0);
        *(bf16x8*)&med[r][128 + c0 + 8] = *(const bf16x8*)(eaord + (size_t)pr * 64 + c0 + 8);
    }
    // med-ready sync is provided by stage-2's first in-loop barrier

    // ---------- stage 2: t2 = relu([m_ed|ea] @ eu1W^T + eu1b)  [64x128, K=192] ----------
    floatx4 acc2[2][4];
#pragma unroll
    for (int mt = 0; mt < 2; mt++)
#pragma unroll
        for (int nt = 0; nt < 4; nt++) acc2[mt][nt] = z4;

    for (int k0 = 0; k0 < 192; k0 += 32) {
        int wr = tid & 127, wc = (tid >> 7) * 16;
        bf16x8 w0 = *(const bf16x8*)(eu1W + (size_t)wr * 192 + k0 + wc);
        bf16x8 w1 = *(const bf16x8*)(eu1W + (size_t)wr * 192 + k0 + wc + 8);
        __syncthreads();
        *(bf16x8*)&Ws[wr][wc]     = w0;
        *(bf16x8*)&Ws[wr][wc + 8] = w1;
        __syncthreads();
        bf16x8 af[2], bv[4];
        af[0] = *(const bf16x8*)&med[wm1 + fr][k0 + fk];
        af[1] = *(const bf16x8*)&med[wm1 + 16 + fr][k0 + fk];
#pragma unroll
        for (int nt = 0; nt < 4; nt++) bv[nt] = *(const bf16x8*)&Ws[wn1 + nt * 16 + fr][fk];
#pragma unroll
        for (int mt = 0; mt < 2; mt++)
#pragma unroll
            for (int nt = 0; nt < 4; nt++)
                acc2[mt][nt] = __builtin_amdgcn_mfma_f32_16x16x32_bf16(af[mt], bv[nt], acc2[mt][nt], 0, 0, 0);
    }
    // t2s region is disjoint from med and Ws — no barrier needed before writes
#pragma unroll
    for (int mt = 0; mt < 2; mt++)
#pragma unroll
        for (int nt = 0; nt < 4; nt++)
#pragma unroll
            for (int i = 0; i < 4; i++) {
                int row = wm1 + mt * 16 + cr + i;
                int col = wn1 + nt * 16 + cc;
                t2s[row][col] = (bf16)fmaxf(acc2[mt][nt][i] + eu1b[col], 0.f);
            }
    // t2s-ready sync is provided by stage-3's first in-loop barrier

    // ---------- stage 3: ea' = t2 @ eu2W^T + eu2b  [64x64, K=128] ----------
    const int wm3 = (wave & 1) * 32, wn3 = (wave >> 1) * 32;
    floatx4 acc3[2][2];
#pragma unroll
    for (int mt = 0; mt < 2; mt++)
#pragma unroll
        for (int nt = 0; nt < 2; nt++) acc3[mt][nt] = z4;

    for (int k0 = 0; k0 < 128; k0 += 32) {
        int wr = tid & 63, wc = (tid >> 6) * 8;
        bf16x8 w0 = *(const bf16x8*)(eu2W + (size_t)wr * 128 + k0 + wc);
        __syncthreads();
        *(bf16x8*)&Ws[wr][wc] = w0;
        __syncthreads();
        bf16x8 af[2], bv[2];
        af[0] = *(const bf16x8*)&t2s[wm3 + fr][k0 + fk];
        af[1] = *(const bf16x8*)&t2s[wm3 + 16 + fr][k0 + fk];
#pragma unroll
        for (int nt = 0; nt < 2; nt++) bv[nt] = *(const bf16x8*)&Ws[wn3 + nt * 16 + fr][fk];
#pragma unroll
        for (int mt = 0; mt < 2; mt++)
#pragma unroll
            for (int nt = 0; nt < 2; nt++)
                acc3[mt][nt] = __builtin_amdgcn_mfma_f32_16x16x32_bf16(af[mt], bv[nt], acc3[mt][nt], 0, 0, 0);
    }
#pragma unroll
    for (int mt = 0; mt < 2; mt++)
#pragma unroll
        for (int nt = 0; nt < 2; nt++)
#pragma unroll
            for (int i = 0; i < 4; i++) {
                int row = wm3 + mt * 16 + cr + i;
                int col = wn3 + nt * 16 + cc;
                float v = acc3[mt][nt][i] + eu2b[col];
                int e = e0 + row;
                eaord[(size_t)pos[e] * 64 + col] = (bf16)v;
                if (ea_out_f) ea_out_f[(size_t)e * 64 + col] = v;  // final layer only
            }
}

// ---------------------------------------------------------------------------
// Post-MLP per-tower MFMA GEMM — consumes bf16 agg buffers (identical
// rounding point; vectorized bf16x8 loads)
// ---------------------------------------------------------------------------
__global__ __launch_bounds__(256) void k_postg(
    const bf16* __restrict__ xin, const bf16* __restrict__ aggX,
    const bf16* __restrict__ aggS, const bf16* __restrict__ aggM,
    const bf16* __restrict__ qWbf, const float* __restrict__ qb,
    bf16* __restrict__ ybf)
{
    __shared__ bf16 As[64][40];
    __shared__ bf16 Ws[32][40];
    const int n0 = blockIdx.x * 64, t = blockIdx.y;
    const int tid = threadIdx.x, wave = tid >> 6, lane = tid & 63;
    const int lrow = tid >> 2, lcol = (tid & 3) * 8;
    const int fr = lane & 15, fk = (lane >> 4) * 8;
    floatx4 acc0 = {0,0,0,0}, acc1 = {0,0,0,0};

    for (int k0 = 0; k0 < 512; k0 += 32) {
        int n = n0 + lrow;
        int c0 = k0 + lcol;
        const bf16* srcp;
        if (c0 < 128)      srcp = xin  + (size_t)n * 128 + c0;
        else if (c0 < 256) srcp = aggX + (size_t)n * 512 + t * 128 + (c0 - 128);
        else if (c0 < 384) srcp = aggS + (size_t)n * 512 + t * 128 + (c0 - 256);
        else               srcp = aggM + (size_t)n * 512 + t * 128 + (c0 - 384);
        bf16x8 a8 = *(const bf16x8*)srcp;
        bf16 w8[8];
        if (tid < 128) {
            int wr = tid >> 2, wc = (tid & 3) * 8;
            *(bf16x8*)w8 = *(const bf16x8*)(qWbf + (size_t)(t * 32 + wr) * 512 + k0 + wc);
        }
        __syncthreads();
        *(bf16x8*)&As[lrow][lcol] = a8;
        if (tid < 128) {
            int wr = tid >> 2, wc = (tid & 3) * 8;
            *(bf16x8*)&Ws[wr][wc] = *(bf16x8*)w8;
        }
        __syncthreads();
        bf16x8 a  = *(const bf16x8*)&As[wave * 16 + fr][fk];
        bf16x8 b0 = *(const bf16x8*)&Ws[fr][fk];
        bf16x8 b1 = *(const bf16x8*)&Ws[16 + fr][fk];
        acc0 = __builtin_amdgcn_mfma_f32_16x16x32_bf16(a, b0, acc0, 0, 0, 0);
        acc1 = __builtin_amdgcn_mfma_f32_16x16x32_bf16(a, b1, acc1, 0, 0, 0);
    }
    const int cc = lane & 15, cr = (lane >> 4) * 4;
#pragma unroll
    for (int i = 0; i < 4; i++) {
        int gn = n0 + wave * 16 + cr + i;
        ybf[(size_t)gn * 128 + t * 32 + cc]      = (bf16)(acc0[i] + qb[t * 32 + cc]);
        ybf[(size_t)gn * 128 + t * 32 + 16 + cc] = (bf16)(acc1[i] + qb[t * 32 + 16 + cc]);
    }
}

// ---------------------------------------------------------------------------
// Fold edge-encoder into pre-MLP; writes zero-extended bias [1024].
// ---------------------------------------------------------------------------
__global__ __launch_bounds__(64) void k_wcomb(
    const float* __restrict__ preW, const float* __restrict__ encW,
    const float* __restrict__ encb, const float* __restrict__ preb,
    bf16* __restrict__ wcomb, float* __restrict__ bcombext)
{
    int tf = blockIdx.x, d = threadIdx.x;
    __shared__ float pw[128];
    __shared__ float red[64];
    const float* pr = preW + (size_t)tf * 384 + 256;
    pw[d]      = pr[d];
    pw[d + 64] = pr[d + 64];
    __syncthreads();
    float acc = 0.f;
    for (int h = 0; h < 128; h++) acc += pw[h] * encW[h * 64 + d];
    wcomb[tf * 64 + d] = (bf16)acc;
    float b = pw[d] * encb[d] + pw[d + 64] * encb[d + 64];
    red[d] = b;
    __syncthreads();
    for (int s = 32; s > 0; s >>= 1) { if (d < s) red[d] += red[d + s]; __syncthreads(); }
    if (d == 0) {
        bcombext[tf] = red[0] + preb[tf];
        bcombext[512 + tf] = 0.f;
    }
}

// ---------------- weight repacks (once per launch) --------------------------
__global__ void k_rep_node(const bf16* __restrict__ preWbf, bf16* __restrict__ Wnode)
{
    int i = blockIdx.x * 256 + threadIdx.x;   // 3*1024*128
    int l = i >> 17, rem = i & 131071;
    int r = rem >> 7, c = rem & 127;
    bf16 v = (r < 512) ? preWbf[(size_t)l * 196608 + (size_t)r * 384 + c]
                       : preWbf[(size_t)l * 196608 + (size_t)(r - 512) * 384 + 128 + c];
    Wnode[i] = v;
}

__global__ void k_rep_em1(const bf16* __restrict__ em1Wbf, bf16* __restrict__ Wem1)
{
    int i = blockIdx.x * 256 + threadIdx.x;   // 512*128
    int r = i >> 7, c = i & 127;
    bf16 v = (r < 256) ? em1Wbf[(size_t)r * 256 + c]
                       : em1Wbf[(size_t)(r - 256) * 256 + 128 + c];
    Wem1[i] = v;
}

__global__ void k_ext_em1b(const float* __restrict__ em1b, float* __restrict__ ext)
{
    int i = blockIdx.x * 256 + threadIdx.x;   // 512
    ext[i] = (i < 256) ? em1b[i] : 0.f;
}

// ----------------------- CSR build -----------------------------------------
__global__ void k_count(const int* __restrict__ dst, int* __restrict__ counts)
{
    int e = blockIdx.x * 256 + threadIdx.x;
    atomicAdd(&counts[dst[e]], 1);
}

__global__ __launch_bounds__(1024) void k_scan(
    const int* __restrict__ counts, int* __restrict__ offs, int* __restrict__ cursor)
{
    __shared__ int ls[1024];
    int tid = threadIdx.x, base = tid * 4;
    int c0 = counts[base], c1 = counts[base + 1], c2 = counts[base + 2], c3 = counts[base + 3];
    ls[tid] = c0 + c1 + c2 + c3;
    __syncthreads();
    for (int d = 1; d < 1024; d <<= 1) {
        int v = (tid >= d) ? ls[tid - d] : 0;
        __syncthreads();
        ls[tid] += v;
        __syncthreads();
    }
    int r = tid ? ls[tid - 1] : 0;
    offs[base] = r;     cursor[base] = r;     r += c0;
    offs[base + 1] = r; cursor[base + 1] = r; r += c1;
    offs[base + 2] = r; cursor[base + 2] = r; r += c2;
    offs[base + 3] = r; cursor[base + 3] = r; r += c3;
    if (tid == 1023) offs[4096] = r;
}

__global__ void k_fill(const int* __restrict__ dst, const int* __restrict__ srcW,
                       int* __restrict__ cursor, int* __restrict__ pos,
                       int* __restrict__ srcord)
{
    int e = blockIdx.x * 256 + threadIdx.x;
    int p = atomicAdd(&cursor[dst[e]], 1);
    pos[e] = p;
    srcord[p] = srcW[e];
}

// ---------------------------------------------------------------------------
// Single-pass aggregation; outputs bf16 (postg casts to bf16 anyway —
// identical rounding point, halves agg-buffer HBM traffic both directions)
// ---------------------------------------------------------------------------
__global__ __launch_bounds__(128) void k_agg(
    const float* __restrict__ PdPs, const bf16* __restrict__ Qord,
    const int* __restrict__ srcord, const int* __restrict__ offs,
    bf16* __restrict__ aggX, bf16* __restrict__ aggS, bf16* __restrict__ aggM)
{
    int n = blockIdx.x, tid = threadIdx.x;
    int c = tid * 4;
    float4 pd = *(const float4*)(PdPs + (size_t)n * 1024 + c);
    float s0 = 0, s1 = 0, s2 = 0, s3 = 0;
    float q0 = 0, q1 = 0, q2 = 0, q3 = 0;
    float x0 = -3e38f, x1 = -3e38f, x2 = -3e38f, x3 = -3e38f;
    int beg = offs[n], end = offs[n + 1];
    for (int i = beg; i < end; i++) {
        int sn = srcord[i];
        float4 ps = *(const float4*)(PdPs + (size_t)sn * 1024 + 512 + c);
        bf16x4 qv = *(const bf16x4*)(Qord + (size_t)i * 512 + c);
        float m0 = pd.x + ps.x + (float)qv[0];
        float m1 = pd.y + ps.y + (float)qv[1];
        float m2 = pd.z + ps.z + (float)qv[2];
        float m3 = pd.w + ps.w + (float)qv[3];
        s0 += m0; s1 += m1; s2 += m2; s3 += m3;
        q0 += m0 * m0; q1 += m1 * m1; q2 += m2 * m2; q3 += m3 * m3;
        x0 = fmaxf(x0, m0); x1 = fmaxf(x1, m1); x2 = fmaxf(x2, m2); x3 = fmaxf(x3, m3);
    }
    int cnt = end - beg;
    float inv = 1.f / fmaxf((float)cnt, 1.f);
    float me0 = s0 * inv, me1 = s1 * inv, me2 = s2 * inv, me3 = s3 * inv;
    float v0 = fmaxf(q0 * inv - me0 * me0, 0.f);
    float v1 = fmaxf(q1 * inv - me1 * me1, 0.f);
    float v2 = fmaxf(q2 * inv - me2 * me2, 0.f);
    float v3 = fmaxf(q3 * inv - me3 * me3, 0.f);
    size_t o = (size_t)n * 512 + c;
    bf16x4 mx, st, me;
    mx[0] = (bf16)(cnt > 0 ? x0 : 0.f); mx[1] = (bf16)(cnt > 0 ? x1 : 0.f);
    mx[2] = (bf16)(cnt > 0 ? x2 : 0.f); mx[3] = (bf16)(cnt > 0 ? x3 : 0.f);
    st[0] = (bf16)sqrtf(v0 + 1e-5f); st[1] = (bf16)sqrtf(v1 + 1e-5f);
    st[2] = (bf16)sqrtf(v2 + 1e-5f); st[3] = (bf16)sqrtf(v3 + 1e-5f);
    me[0] = (bf16)me0; me[1] = (bf16)me1; me[2] = (bf16)me2; me[3] = (bf16)me3;
    *(bf16x4*)(aggX + o) = mx;
    *(bf16x4*)(aggS + o) = st;
    *(bf16x4*)(aggM + o) = me;
}

// --------------------------- GRU elementwise --------------------------------
// fo != nullptr on the final layer: writes out directly into d_out (both the
// leading and trailing out-copies), eliminating k_writeout entirely.
__global__ void k_gru(const float* __restrict__ gi, const float* __restrict__ gh,
                      float* __restrict__ hst, bf16* __restrict__ ob,
                      float* __restrict__ fo)
{
    int i = blockIdx.x * 256 + threadIdx.x;
    int k = i & 127;
    size_t b = (size_t)(i >> 7) * 384;
    float ir = gi[b + k],       hr = gh[b + k];
    float iz = gi[b + 128 + k], hz = gh[b + 128 + k];
    float ic = gi[b + 256 + k], hc = gh[b + 256 + k];
    float r = 1.f / (1.f + __expf(-(ir + hr)));
    float z = 1.f / (1.f + __expf(-(iz + hz)));
    float c = tanhf(ic + r * hc);
    float h = hst[i];
    float hn = (1.f - z) * c + z * h;
    hst[i] = hn;
    ob[i] = (bf16)hn;
    if (fo) { fo[i] = hn; fo[4718592 + i] = hn; }
}

__global__ void k_sentinel(float* __restrict__ o, float v)
{
    int i = blockIdx.x * 256 + threadIdx.x;
    o[i] = v;
}

// ===========================================================================
extern "C" void kernel_launch(void* const* d_in, const int* in_sizes, int n_in,
                              void* d_out, int out_size, void* d_ws, size_t ws_size,
                              hipStream_t stream)
{
    static const int exp_sizes[23] = {
        524288, 4194304, 131072, 24576, 384, 589824, 1536, 196608, 384,
        49152, 384, 49152, 49152, 384, 384, 65536, 256, 32768, 128,
        24576, 128, 8192, 64 };
    if (n_in != 23) { k_sentinel<<<2048, 256, 0, stream>>>((float*)d_out, 200.f); return; }
    for (int i = 0; i < 23; i++)
        if (in_sizes[i] != exp_sizes[i]) {
            k_sentinel<<<2048, 256, 0, stream>>>((float*)d_out, 60.f + 4.f * i);
            return;
        }
    if (out_size != 5242880) { k_sentinel<<<2048, 256, 0, stream>>>((float*)d_out, 52.f); return; }

    const int* eidx = (const int*)d_in[2];

    char* w = (char*)d_ws;
    size_t off = 0;
    auto alloc = [&](size_t bytes) -> char* {
        char* p = w + off;
        off = (off + bytes + 255) & ~(size_t)255;
        return p;
    };
    int*   dflag   = (int*)  alloc(256);
    int*   iflag   = (int*)  alloc(256);
    int*   srcW    = (int*)  alloc((size_t)EE * 4);
    int*   dstW    = (int*)  alloc((size_t)EE * 4);
    int*   pos     = (int*)  alloc((size_t)EE * 4);
    int*   srcord  = (int*)  alloc((size_t)EE * 4);
    float* out_f32 = (float*)alloc((size_t)NN * HH * 4);
    bf16*  out_bf  = (bf16*) alloc((size_t)NN * HH * 2);
    bf16*  m_bf    = (bf16*) alloc((size_t)NN * HH * 2);
    bf16*  ybf     = (bf16*) alloc((size_t)NN * HH * 2);
    bf16*  eaord   = (bf16*) alloc((size_t)EE * EDD * 2);
    bf16*  wcombBf = (bf16*) alloc((size_t)THD * EDD * 2);
    float* bcombx  = (float*)alloc((size_t)1024 * 4);
    int*   counts  = (int*)  alloc((size_t)NN * 4);
    int*   offs    = (int*)  alloc((size_t)(NN + 1) * 4);
    int*   cursor  = (int*)  alloc((size_t)NN * 4);
    float* PdPs    = (float*)alloc((size_t)NN * 1024 * 4);
    bf16*  aggX    = (bf16*) alloc((size_t)NN * THD * 2);
    bf16*  aggS    = (bf16*) alloc((size_t)NN * THD * 2);
    bf16*  aggM    = (bf16*) alloc((size_t)NN * THD * 2);
    float* encWc  = (float*)alloc((size_t)24576 * 4);
    float* encbc  = (float*)alloc((size_t)384 * 4);
    float* preWc  = (float*)alloc((size_t)589824 * 4);
    float* prebc  = (float*)alloc((size_t)1536 * 4);
    float* postbc = (float*)alloc((size_t)384 * 4);
    float* linbc  = (float*)alloc((size_t)384 * 4);
    float* bihc   = (float*)alloc((size_t)384 * 4);
    float* bhhc   = (float*)alloc((size_t)384 * 4);
    float* em1bc  = (float*)alloc((size_t)256 * 4);
    float* em1ext = (float*)alloc((size_t)512 * 4);
    float* em2bc  = (float*)alloc((size_t)128 * 4);
    float* eu1bc  = (float*)alloc((size_t)128 * 4);
    float* eu2bc  = (float*)alloc((size_t)64 * 4);
    bf16* preWbf = (bf16*)alloc((size_t)589824 * 2);
    bf16* WnodeBf= (bf16*)alloc((size_t)3 * 131072 * 2);
    bf16* postWbf= (bf16*)alloc((size_t)196608 * 2);
    bf16* linWbf = (bf16*)alloc((size_t)49152 * 2);
    bf16* WihBf  = (bf16*)alloc((size_t)49152 * 2);
    bf16* WhhBf  = (bf16*)alloc((size_t)49152 * 2);
    bf16* em1Wbf = (bf16*)alloc((size_t)65536 * 2);
    bf16* Wem1Bf = (bf16*)alloc((size_t)65536 * 2);
    bf16* em2Wbf = (bf16*)alloc((size_t)32768 * 2);
    bf16* eu1Wbf = (bf16*)alloc((size_t)24576 * 2);
    bf16* eu2Wbf = (bf16*)alloc((size_t)8192 * 2);
    // phase-shared region: Q_ord (PNA) / gi,gh (GRU) / SAB (edge)
    char* region = alloc((size_t)EE * 512 * 2);     // 67.1 MB
    bf16*  Qord = (bf16*) (region);
    float* gi   = (float*)(region);
    float* gh   = (float*)(region + 6291456);
    float* SAB  = (float*)(region);                 // [N,512] f32

    if (ws_size < off) { k_sentinel<<<2048, 256, 0, stream>>>((float*)d_out, 44.f); return; }

    // ---- index canonicalize + CSR ----
    k_detidx<<<1, 64, 0, stream>>>(eidx, iflag);
    k_extidx<<<EE / 256, 256, 0, stream>>>(eidx, srcW, dstW, iflag);
    hipMemsetAsync(counts, 0, NN * 4, stream);
    k_count<<<EE / 256, 256, 0, stream>>>(dstW, counts);
    k_scan<<<1, 1024, 0, stream>>>(counts, offs, cursor);
    k_fill<<<EE / 256, 256, 0, stream>>>(dstW, srcW, cursor, pos, srcord);

    // ---- float canonicalize ----
    k_detect<<<1, 64, 0, stream>>>(d_in[1], dflag);
    auto CF = [&](int idx, float* dst, int n) {
        k_canon_f<<<(n + 255) / 256, 256, 0, stream>>>(d_in[idx], dst, n, dflag);
    };
    auto CB = [&](int idx, bf16* dst, int n) {
        k_canon_b<<<(n + 255) / 256, 256, 0, stream>>>(d_in[idx], dst, n, dflag);
    };
    k_canon_fb<<<(NN * HH + 255) / 256, 256, 0, stream>>>(d_in[0], out_f32, out_bf, NN * HH, dflag);
    k_canon_ea<<<(EE * EDD + 255) / 256, 256, 0, stream>>>(d_in[1], eaord, pos, dflag);
    k_canon_fb<<<(589824 + 255) / 256, 256, 0, stream>>>(d_in[5], preWc, preWbf, 589824, dflag);
    CF(3, encWc, 24576);   CF(4, encbc, 384);   CF(6, prebc, 1536);
    CF(8, postbc, 384);    CF(10, linbc, 384);  CF(13, bihc, 384);  CF(14, bhhc, 384);
    CF(16, em1bc, 256);    CF(18, em2bc, 128);  CF(20, eu1bc, 128); CF(22, eu2bc, 64);
    CB(7, postWbf, 196608); CB(9, linWbf, 49152);
    CB(11, WihBf, 49152);   CB(12, WhhBf, 49152);
    CB(15, em1Wbf, 65536);  CB(17, em2Wbf, 32768);
    CB(19, eu1Wbf, 24576);  CB(21, eu2Wbf, 8192);
    // repacks
    k_rep_node<<<(3 * 131072) / 256, 256, 0, stream>>>(preWbf, WnodeBf);
    k_rep_em1<<<65536 / 256, 256, 0, stream>>>(em1Wbf, Wem1Bf);
    k_ext_em1b<<<2, 256, 0, stream>>>(em1bc, em1ext);

    auto GEMM = [&](const bf16* A, int lda, const bf16* Wm, int ldw, const float* bias,
                    void* C, int ldc, int M, int Nout, int K, bool relu, int om) {
        dim3 grid(M / 64, Nout / 64);
        if (relu) {
            if (om) k_mgemm<true, 1><<<grid, 256, 0, stream>>>(A, lda, Wm, ldw, bias, C, ldc, K);
            else    k_mgemm<true, 0><<<grid, 256, 0, stream>>>(A, lda, Wm, ldw, bias, C, ldc, K);
        } else {
            if (om) k_mgemm<false, 1><<<grid, 256, 0, stream>>>(A, lda, Wm, ldw, bias, C, ldc, K);
            else    k_mgemm<false, 0><<<grid, 256, 0, stream>>>(A, lda, Wm, ldw, bias, C, ldc, K);
        }
    };

    for (int l = 0; l < 3; l++) {
        const float* preW_l  = preWc  + (size_t)l * 196608;
        const float* encW_l  = encWc  + (size_t)l * 8192;
        const float* encb_l  = encbc  + (size_t)l * 128;
        const float* preb_l  = prebc  + (size_t)l * 512;
        const bf16*  Wnode_l = WnodeBf + (size_t)l * 131072;
        const bf16*  postW_l = postWbf + (size_t)l * 65536;
        const float* postb_l = postbc + (size_t)l * 128;
        const bf16*  linW_l  = linWbf + (size_t)l * 16384;
        const float* linb_l  = linbc  + (size_t)l * 128;
        const bool last = (l == 2);

        // ---- PNA ----
        k_wcomb<<<THD, 64, 0, stream>>>(preW_l, encW_l, encb_l, preb_l, wcombBf, bcombx);
        GEMM(out_bf, HH, Wnode_l, 128, bcombx, PdPs, 1024, NN, 1024, HH, false, 0);
        k_qgemm<<<dim3(EE / 64, 2), 256, 0, stream>>>(eaord, wcombBf, Qord);
        k_agg<<<NN, 128, 0, stream>>>(PdPs, Qord, srcord, offs, aggX, aggS, aggM);
        k_postg<<<dim3(NN / 64, 4), 256, 0, stream>>>(out_bf, aggX, aggS, aggM,
                                                      postW_l, postb_l, ybf);
        GEMM(ybf, HH, linW_l, HH, linb_l, m_bf, HH, NN, HH, HH, true, 1);
        // ---- GRU ----
        GEMM(m_bf,   HH, WihBf, HH, bihc, gi, 384, NN, 384, HH, false, 0);
        GEMM(out_bf, HH, WhhBf, HH, bhhc, gh, 384, NN, 384, HH, false, 0);
        k_gru<<<NN * HH / 256, 256, 0, stream>>>(gi, gh, out_f32, out_bf,
                                                 last ? (float*)d_out : (float*)nullptr);
        // ---- edge update (merged SAB + fused chain) ----
        GEMM(out_bf, HH, Wem1Bf, 128, em1ext, SAB, 512, NN, 512, HH, false, 0);
        k_edge<<<EE / 64, 256, 0, stream>>>(SAB, em2Wbf, em2bc, eu1Wbf, eu1bc,
                                            eu2Wbf, eu2bc, srcW, dstW, pos,
                                            eaord, last ? (float*)d_out + 524288 : (float*)nullptr);
    }
}

// Round 3
// 567.507 us; speedup vs baseline: 1.1392x; 1.0659x over previous
//
#include <hip/hip_runtime.h>
#include <hip/hip_bf16.h>
#include <math.h>

#define NN 4096
#define EE 65536
#define HH 128
#define EDD 64
#define THD 512

typedef __bf16 bf16;
typedef __bf16 bf16x8 __attribute__((ext_vector_type(8)));
typedef __bf16 bf16x4 __attribute__((ext_vector_type(4)));
typedef float  floatx4 __attribute__((ext_vector_type(4)));

// ---------------------------------------------------------------------------
// input dtype detects (proven: floats f32, edge_index int32; cheap insurance)
// ---------------------------------------------------------------------------
__global__ __launch_bounds__(64) void k_detect(const void* __restrict__ p,
                                               int* __restrict__ flag)
{
    const bf16* b = (const bf16*)p;
    int t = threadIdx.x;
    int bad = 0;
    for (int i = 0; i < 32; i++) {
        float v = (float)b[t * 32 + i];
        if (!(v == v) || fabsf(v) > 100.f) bad = 1;
    }
    unsigned long long m = __ballot(bad);
    if (t == 0) *flag = (m == 0ULL) ? 1 : 0;
}

__global__ void k_canon_f(const void* __restrict__ src, float* __restrict__ dst,
                          int n, const int* __restrict__ flag)
{
    int i = blockIdx.x * 256 + threadIdx.x;
    if (i >= n) return;
    dst[i] = (*flag) ? (float)((const bf16*)src)[i] : ((const float*)src)[i];
}

__global__ void k_canon_b(const void* __restrict__ src, bf16* __restrict__ dst,
                          int n, const int* __restrict__ flag)
{
    int i = blockIdx.x * 256 + threadIdx.x;
    if (i >= n) return;
    dst[i] = (*flag) ? ((const bf16*)src)[i] : (bf16)((const float*)src)[i];
}

__global__ void k_canon_fb(const void* __restrict__ src, float* __restrict__ dst,
                           bf16* __restrict__ dst2, int n, const int* __restrict__ flag)
{
    int i = blockIdx.x * 256 + threadIdx.x;
    if (i >= n) return;
    float v = (*flag) ? (float)((const bf16*)src)[i] : ((const float*)src)[i];
    dst[i] = v;
    dst2[i] = (bf16)v;
}

// ea canon: CSR-ordered bf16 only (f32 ea only needed as FINAL output,
// written directly to d_out by layer-3 k_edge)
__global__ void k_canon_ea(const void* __restrict__ src,
                           bf16* __restrict__ eaord, const int* __restrict__ pos,
                           const int* __restrict__ flag)
{
    int i = blockIdx.x * 256 + threadIdx.x;   // E*64
    int e = i >> 6, d = i & 63;
    float v = (*flag) ? (float)((const bf16*)src)[i] : ((const float*)src)[i];
    eaord[(size_t)pos[e] * 64 + d] = (bf16)v;
}

__global__ __launch_bounds__(64) void k_detidx(const int* __restrict__ p,
                                               int* __restrict__ iflag)
{
    int t = threadIdx.x;
    int bad = 0;
    for (int i = 0; i < 8; i++) {
        int k = t * 8 + i;
        int lo = p[2 * k], hi = p[2 * k + 1];
        if (hi != 0 || lo < 0 || lo >= NN) bad = 1;
    }
    unsigned long long m = __ballot(bad);
    if (t == 0) *iflag = (m == 0ULL) ? 1 : 0;
}

__global__ void k_extidx(const int* __restrict__ p, int* __restrict__ srcW,
                         int* __restrict__ dstW, const int* __restrict__ iflag)
{
    int e = blockIdx.x * 256 + threadIdx.x;
    int s, d;
    if (*iflag) { s = p[2 * e];  d = p[2 * EE + 2 * e]; }
    else        { s = p[e];      d = p[EE + e]; }
    srcW[e] = min(max(s, 0), NN - 1);
    dstW[e] = min(max(d, 0), NN - 1);
}

// ---------------------------------------------------------------------------
// MFMA bf16 GEMM (validated): C[M,Nout] = act(A @ W^T + bias)
// ---------------------------------------------------------------------------
template<bool RELU, int OM>
__global__ __launch_bounds__(256) void k_mgemm(
    const bf16* __restrict__ A, int lda,
    const bf16* __restrict__ W, int ldw, const float* __restrict__ bias,
    void* __restrict__ Cv, int ldc, int K)
{
    __shared__ bf16 As[64][40];
    __shared__ bf16 Ws[64][40];
    const int m0 = blockIdx.x * 64, n0 = blockIdx.y * 64;
    const int tid = threadIdx.x, wave = tid >> 6, lane = tid & 63;
    const int wm = (wave & 1) * 32, wn = (wave >> 1) * 32;
    const int lrow = tid >> 2, lcol = (tid & 3) * 8;
    const int fr = lane & 15, fk = (lane >> 4) * 8;
    floatx4 acc00 = {0,0,0,0}, acc01 = {0,0,0,0}, acc10 = {0,0,0,0}, acc11 = {0,0,0,0};

    for (int k0 = 0; k0 < K; k0 += 32) {
        bf16x8 av = *(const bf16x8*)(A + (size_t)(m0 + lrow) * lda + k0 + lcol);
        bf16x8 wv = *(const bf16x8*)(W + (size_t)(n0 + lrow) * ldw + k0 + lcol);
        __syncthreads();
        *(bf16x8*)&As[lrow][lcol] = av;
        *(bf16x8*)&Ws[lrow][lcol] = wv;
        __syncthreads();
        bf16x8 a0 = *(const bf16x8*)&As[wm + fr][fk];
        bf16x8 a1 = *(const bf16x8*)&As[wm + 16 + fr][fk];
        bf16x8 b0 = *(const bf16x8*)&Ws[wn + fr][fk];
        bf16x8 b1 = *(const bf16x8*)&Ws[wn + 16 + fr][fk];
        acc00 = __builtin_amdgcn_mfma_f32_16x16x32_bf16(a0, b0, acc00, 0, 0, 0);
        acc01 = __builtin_amdgcn_mfma_f32_16x16x32_bf16(a0, b1, acc01, 0, 0, 0);
        acc10 = __builtin_amdgcn_mfma_f32_16x16x32_bf16(a1, b0, acc10, 0, 0, 0);
        acc11 = __builtin_amdgcn_mfma_f32_16x16x32_bf16(a1, b1, acc11, 0, 0, 0);
    }
    const int cc = lane & 15, cr = (lane >> 4) * 4;
    float vb0 = bias ? bias[n0 + wn + cc] : 0.f;
    float vb1 = bias ? bias[n0 + wn + 16 + cc] : 0.f;
    floatx4 accs[2][2] = {{acc00, acc01}, {acc10, acc11}};
#pragma unroll
    for (int mt = 0; mt < 2; mt++)
#pragma unroll
        for (int nt = 0; nt < 2; nt++) {
            float vb = nt ? vb1 : vb0;
#pragma unroll
            for (int i = 0; i < 4; i++) {
                int gm = m0 + wm + mt * 16 + cr + i;
                int gn = n0 + wn + nt * 16 + cc;
                float v = accs[mt][nt][i] + vb;
                if (RELU) v = fmaxf(v, 0.f);
                if (OM == 1) ((bf16*)Cv)[(size_t)gm * ldc + gn] = (bf16)v;
                else         ((float*)Cv)[(size_t)gm * ldc + gn] = v;
            }
        }
}

// ---------------------------------------------------------------------------
// Q GEMM, wide tile: Q_ord[E,512] = eaord[E,64] @ wcomb[512,64]^T
// ---------------------------------------------------------------------------
__global__ __launch_bounds__(256) void k_qgemm(
    const bf16* __restrict__ eaord, const bf16* __restrict__ wcomb,
    bf16* __restrict__ Qord)
{
    __shared__ bf16 As[64][72];
    __shared__ bf16 Ws[256][72];
    const int e0 = blockIdx.x * 64, n0g = blockIdx.y * 256;
    const int tid = threadIdx.x, wave = tid >> 6, lane = tid & 63;
    const int fr = lane & 15, fk = (lane >> 4) * 8;
    const int cc = lane & 15, cr = (lane >> 4) * 4;

#pragma unroll
    for (int v = 0; v < 2; v++) {
        int lin = v * 2048 + tid * 8;
        int r = lin >> 6, c = lin & 63;
        *(bf16x8*)&As[r][c] = *(const bf16x8*)(eaord + (size_t)(e0 + r) * 64 + c);
    }
#pragma unroll
    for (int v = 0; v < 8; v++) {
        int lin = v * 2048 + tid * 8;
        int r = lin >> 6, c = lin & 63;
        *(bf16x8*)&Ws[r][c] = *(const bf16x8*)(wcomb + (size_t)(n0g + r) * 64 + c);
    }
    __syncthreads();

    floatx4 acc[4][4];
#pragma unroll
    for (int mt = 0; mt < 4; mt++)
#pragma unroll
        for (int nt = 0; nt < 4; nt++) acc[mt][nt] = (floatx4){0,0,0,0};

#pragma unroll
    for (int kk = 0; kk < 64; kk += 32) {
        bf16x8 af[4], bv[4];
#pragma unroll
        for (int mt = 0; mt < 4; mt++) af[mt] = *(const bf16x8*)&As[mt * 16 + fr][kk + fk];
#pragma unroll
        for (int nt = 0; nt < 4; nt++) bv[nt] = *(const bf16x8*)&Ws[wave * 64 + nt * 16 + fr][kk + fk];
#pragma unroll
        for (int mt = 0; mt < 4; mt++)
#pragma unroll
            for (int nt = 0; nt < 4; nt++)
                acc[mt][nt] = __builtin_amdgcn_mfma_f32_16x16x32_bf16(af[mt], bv[nt], acc[mt][nt], 0, 0, 0);
    }
#pragma unroll
    for (int mt = 0; mt < 4; mt++)
#pragma unroll
        for (int nt = 0; nt < 4; nt++)
#pragma unroll
            for (int i = 0; i < 4; i++) {
                int row = mt * 16 + cr + i;
                int col = n0g + wave * 64 + nt * 16 + cc;
                Qord[(size_t)(e0 + row) * 512 + col] = (bf16)acc[mt][nt][i];
            }
}

// ---------------------------------------------------------------------------
// Fused edge update — REVERTED to the R0-proven structure: A computed
// per-k-step from SAB (latency spread across k-steps, overlapped by other
// waves' staging+MFMA) + LDS weight staging. Kept from R1/R2 (strictly less
// work): float4 SAB loads, last-layer-only f32 output, LDS aliasing
// (As aliases t2s) → exactly 53248 B → 3 blocks/CU (R0 was 57 KB → 2).
// ---------------------------------------------------------------------------
__global__ __launch_bounds__(256) void k_edge(
    const float* __restrict__ SAB,
    const bf16* __restrict__ em2W, const float* __restrict__ em2b,
    const bf16* __restrict__ eu1W, const float* __restrict__ eu1b,
    const bf16* __restrict__ eu2W, const float* __restrict__ eu2b,
    const int* __restrict__ src, const int* __restrict__ dst,
    const int* __restrict__ pos,
    bf16* __restrict__ eaord, float* __restrict__ ea_out_f)
{
    __shared__ char smem[53248];
    bf16 (*Ws)[40]   = (bf16 (*)[40])smem;                 // 128x40 = 10240 B
    bf16 (*med)[200] = (bf16 (*)[200])(smem + 10240);      // 64x200 = 25600 B
    bf16 (*As)[40]   = (bf16 (*)[40])(smem + 35840);       // 64x40 = 5120 B (stage 1; aliases t2s)
    bf16 (*t2s)[136] = (bf16 (*)[136])(smem + 35840);      // 64x136 = 17408 B (stages 2-3)

    const int e0 = blockIdx.x * 64;
    const int tid = threadIdx.x, wave = tid >> 6, lane = tid & 63;
    const int lrow = tid >> 2, lcol = (tid & 3) * 8;
    const int fr = lane & 15, fk = (lane >> 4) * 8;
    const int cc = lane & 15, cr = (lane >> 4) * 4;
    const int sI = src[e0 + lrow], dI = dst[e0 + lrow];
    const floatx4 z4 = {0.f, 0.f, 0.f, 0.f};

    // ---------- stage 1: m_ed = relu(A @ em2W^T + em2b)  [64x128, K=256] ----------
    const int wm1 = (wave & 1) * 32, wn1 = (wave >> 1) * 64;
    floatx4 acc1[2][4];
#pragma unroll
    for (int mt = 0; mt < 2; mt++)
#pragma unroll
        for (int nt = 0; nt < 4; nt++) acc1[mt][nt] = z4;

    for (int k0 = 0; k0 < 256; k0 += 32) {
        // A slice: relu(SAB[sI][k0+lcol..+7] + SAB[dI][256+k0+lcol..+7]) — float4 loads
        float4 a0 = *(const float4*)(SAB + (size_t)sI * 512 + k0 + lcol);
        float4 a1 = *(const float4*)(SAB + (size_t)sI * 512 + k0 + lcol + 4);
        float4 b0 = *(const float4*)(SAB + (size_t)dI * 512 + 256 + k0 + lcol);
        float4 b1 = *(const float4*)(SAB + (size_t)dI * 512 + 256 + k0 + lcol + 4);
        bf16 a8[8];
        a8[0] = (bf16)fmaxf(a0.x + b0.x, 0.f); a8[1] = (bf16)fmaxf(a0.y + b0.y, 0.f);
        a8[2] = (bf16)fmaxf(a0.z + b0.z, 0.f); a8[3] = (bf16)fmaxf(a0.w + b0.w, 0.f);
        a8[4] = (bf16)fmaxf(a1.x + b1.x, 0.f); a8[5] = (bf16)fmaxf(a1.y + b1.y, 0.f);
        a8[6] = (bf16)fmaxf(a1.z + b1.z, 0.f); a8[7] = (bf16)fmaxf(a1.w + b1.w, 0.f);
        int wr = tid & 127, wc = (tid >> 7) * 16;
        bf16x8 w0 = *(const bf16x8*)(em2W + (size_t)wr * 256 + k0 + wc);
        bf16x8 w1 = *(const bf16x8*)(em2W + (size_t)wr * 256 + k0 + wc + 8);
        __syncthreads();
        *(bf16x8*)&As[lrow][lcol] = *(bf16x8*)a8;
        *(bf16x8*)&Ws[wr][wc]     = w0;
        *(bf16x8*)&Ws[wr][wc + 8] = w1;
        __syncthreads();
        bf16x8 af[2], bv[4];
        af[0] = *(const bf16x8*)&As[wm1 + fr][fk];
        af[1] = *(const bf16x8*)&As[wm1 + 16 + fr][fk];
#pragma unroll
        for (int nt = 0; nt < 4; nt++) bv[nt] = *(const bf16x8*)&Ws[wn1 + nt * 16 + fr][fk];
#pragma unroll
        for (int mt = 0; mt < 2; mt++)
#pragma unroll
            for (int nt = 0; nt < 4; nt++)
                acc1[mt][nt] = __builtin_amdgcn_mfma_f32_16x16x32_bf16(af[mt], bv[nt], acc1[mt][nt], 0, 0, 0);
    }
    // med region is disjoint from As/Ws — no barrier needed before these writes
#pragma unroll
    for (int mt = 0; mt < 2; mt++)
#pragma unroll
        for (int nt = 0; nt < 4; nt++)
#pragma unroll
            for (int i = 0; i < 4; i++) {
                int row = wm1 + mt * 16 + cr + i;
                int col = wn1 + nt * 16 + cc;
                med[row][col] = (bf16)fmaxf(acc1[mt][nt][i] + em2b[col], 0.f);
            }
    // append ea tile (CSR-ordered rows via pos)
    {
        int r = tid >> 2, c0 = (tid & 3) * 16;
        int pr = pos[e0 + r];
        *(bf16x8*)&med[r][128 + c0]     = *(const bf16x8*)(eaord + (size_t)pr * 64 + c0);
        *(bf16x8*)&med[r][128 + c0 + 8] = *(const bf16x8*)(eaord + (size_t)pr * 64 + c0 + 8);
    }
    // med-ready sync provided by stage-2's first in-loop barrier

    // ---------- stage 2: t2 = relu([m_ed|ea] @ eu1W^T + eu1b)  [64x128, K=192] ----------
    floatx4 acc2[2][4];
#pragma unroll
    for (int mt = 0; mt < 2; mt++)
#pragma unroll
        for (int nt = 0; nt < 4; nt++) acc2[mt][nt] = z4;

    for (int k0 = 0; k0 < 192; k0 += 32) {
        int wr = tid & 127, wc = (tid >> 7) * 16;
        bf16x8 w0 = *(const bf16x8*)(eu1W + (size_t)wr * 192 + k0 + wc);
        bf16x8 w1 = *(const bf16x8*)(eu1W + (size_t)wr * 192 + k0 + wc + 8);
        __syncthreads();
        *(bf16x8*)&Ws[wr][wc]     = w0;
        *(bf16x8*)&Ws[wr][wc + 8] = w1;
        __syncthreads();
        bf16x8 af[2], bv[4];
        af[0] = *(const bf16x8*)&med[wm1 + fr][k0 + fk];
        af[1] = *(const bf16x8*)&med[wm1 + 16 + fr][k0 + fk];
#pragma unroll
        for (int nt = 0; nt < 4; nt++) bv[nt] = *(const bf16x8*)&Ws[wn1 + nt * 16 + fr][fk];
#pragma unroll
        for (int mt = 0; mt < 2; mt++)
#pragma unroll
            for (int nt = 0; nt < 4; nt++)
                acc2[mt][nt] = __builtin_amdgcn_mfma_f32_16x16x32_bf16(af[mt], bv[nt], acc2[mt][nt], 0, 0, 0);
    }
    // t2s aliases As (dead since end of stage 1, separated by stage-2 barriers);
    // disjoint from med and Ws — safe to write without an extra barrier
#pragma unroll
    for (int mt = 0; mt < 2; mt++)
#pragma unroll
        for (int nt = 0; nt < 4; nt++)
#pragma unroll
            for (int i = 0; i < 4; i++) {
                int row = wm1 + mt * 16 + cr + i;
                int col = wn1 + nt * 16 + cc;
                t2s[row][col] = (bf16)fmaxf(acc2[mt][nt][i] + eu1b[col], 0.f);
            }
    // t2s-ready sync provided by stage-3's first in-loop barrier

    // ---------- stage 3: ea' = t2 @ eu2W^T + eu2b  [64x64, K=128] ----------
    const int wm3 = (wave & 1) * 32, wn3 = (wave >> 1) * 32;
    floatx4 acc3[2][2];
#pragma unroll
    for (int mt = 0; mt < 2; mt++)
#pragma unroll
        for (int nt = 0; nt < 2; nt++) acc3[mt][nt] = z4;

    for (int k0 = 0; k0 < 128; k0 += 32) {
        int wr = tid & 63, wc = (tid >> 6) * 8;
        bf16x8 w0 = *(const bf16x8*)(eu2W + (size_t)wr * 128 + k0 + wc);
        __syncthreads();
        *(bf16x8*)&Ws[wr][wc] = w0;
        __syncthreads();
        bf16x8 af[2], bv[2];
        af[0] = *(const bf16x8*)&t2s[wm3 + fr][k0 + fk];
        af[1] = *(const bf16x8*)&t2s[wm3 + 16 + fr][k0 + fk];
#pragma unroll
        for (int nt = 0; nt < 2; nt++) bv[nt] = *(const bf16x8*)&Ws[wn3 + nt * 16 + fr][fk];
#pragma unroll
        for (int mt = 0; mt < 2; mt++)
#pragma unroll
            for (int nt = 0; nt < 2; nt++)
                acc3[mt][nt] = __builtin_amdgcn_mfma_f32_16x16x32_bf16(af[mt], bv[nt], acc3[mt][nt], 0, 0, 0);
    }
#pragma unroll
    for (int mt = 0; mt < 2; mt++)
#pragma unroll
        for (int nt = 0; nt < 2; nt++)
#pragma unroll
            for (int i = 0; i < 4; i++) {
                int row = wm3 + mt * 16 + cr + i;
                int col = wn3 + nt * 16 + cc;
                float v = acc3[mt][nt][i] + eu2b[col];
                int e = e0 + row;
                eaord[(size_t)pos[e] * 64 + col] = (bf16)v;
                if (ea_out_f) ea_out_f[(size_t)e * 64 + col] = v;  // final layer only
            }
}

// ---------------------------------------------------------------------------
// Post-MLP per-tower MFMA GEMM — consumes bf16 agg buffers (identical
// rounding point; vectorized bf16x8 loads)
// ---------------------------------------------------------------------------
__global__ __launch_bounds__(256) void k_postg(
    const bf16* __restrict__ xin, const bf16* __restrict__ aggX,
    const bf16* __restrict__ aggS, const bf16* __restrict__ aggM,
    const bf16* __restrict__ qWbf, const float* __restrict__ qb,
    bf16* __restrict__ ybf)
{
    __shared__ bf16 As[64][40];
    __shared__ bf16 Ws[32][40];
    const int n0 = blockIdx.x * 64, t = blockIdx.y;
    const int tid = threadIdx.x, wave = tid >> 6, lane = tid & 63;
    const int lrow = tid >> 2, lcol = (tid & 3) * 8;
    const int fr = lane & 15, fk = (lane >> 4) * 8;
    floatx4 acc0 = {0,0,0,0}, acc1 = {0,0,0,0};

    for (int k0 = 0; k0 < 512; k0 += 32) {
        int n = n0 + lrow;
        int c0 = k0 + lcol;
        const bf16* srcp;
        if (c0 < 128)      srcp = xin  + (size_t)n * 128 + c0;
        else if (c0 < 256) srcp = aggX + (size_t)n * 512 + t * 128 + (c0 - 128);
        else if (c0 < 384) srcp = aggS + (size_t)n * 512 + t * 128 + (c0 - 256);
        else               srcp = aggM + (size_t)n * 512 + t * 128 + (c0 - 384);
        bf16x8 a8 = *(const bf16x8*)srcp;
        bf16 w8[8];
        if (tid < 128) {
            int wr = tid >> 2, wc = (tid & 3) * 8;
            *(bf16x8*)w8 = *(const bf16x8*)(qWbf + (size_t)(t * 32 + wr) * 512 + k0 + wc);
        }
        __syncthreads();
        *(bf16x8*)&As[lrow][lcol] = a8;
        if (tid < 128) {
            int wr = tid >> 2, wc = (tid & 3) * 8;
            *(bf16x8*)&Ws[wr][wc] = *(bf16x8*)w8;
        }
        __syncthreads();
        bf16x8 a  = *(const bf16x8*)&As[wave * 16 + fr][fk];
        bf16x8 b0 = *(const bf16x8*)&Ws[fr][fk];
        bf16x8 b1 = *(const bf16x8*)&Ws[16 + fr][fk];
        acc0 = __builtin_amdgcn_mfma_f32_16x16x32_bf16(a, b0, acc0, 0, 0, 0);
        acc1 = __builtin_amdgcn_mfma_f32_16x16x32_bf16(a, b1, acc1, 0, 0, 0);
    }
    const int cc = lane & 15, cr = (lane >> 4) * 4;
#pragma unroll
    for (int i = 0; i < 4; i++) {
        int gn = n0 + wave * 16 + cr + i;
        ybf[(size_t)gn * 128 + t * 32 + cc]      = (bf16)(acc0[i] + qb[t * 32 + cc]);
        ybf[(size_t)gn * 128 + t * 32 + 16 + cc] = (bf16)(acc1[i] + qb[t * 32 + 16 + cc]);
    }
}

// ---------------------------------------------------------------------------
// Fold edge-encoder into pre-MLP; writes zero-extended bias [1024].
// ---------------------------------------------------------------------------
__global__ __launch_bounds__(64) void k_wcomb(
    const float* __restrict__ preW, const float* __restrict__ encW,
    const float* __restrict__ encb, const float* __restrict__ preb,
    bf16* __restrict__ wcomb, float* __restrict__ bcombext)
{
    int tf = blockIdx.x, d = threadIdx.x;
    __shared__ float pw[128];
    __shared__ float red[64];
    const float* pr = preW + (size_t)tf * 384 + 256;
    pw[d]      = pr[d];
    pw[d + 64] = pr[d + 64];
    __syncthreads();
    float acc = 0.f;
    for (int h = 0; h < 128; h++) acc += pw[h] * encW[h * 64 + d];
    wcomb[tf * 64 + d] = (bf16)acc;
    float b = pw[d] * encb[d] + pw[d + 64] * encb[d + 64];
    red[d] = b;
    __syncthreads();
    for (int s = 32; s > 0; s >>= 1) { if (d < s) red[d] += red[d + s]; __syncthreads(); }
    if (d == 0) {
        bcombext[tf] = red[0] + preb[tf];
        bcombext[512 + tf] = 0.f;
    }
}

// ---------------- weight repacks (once per launch) --------------------------
__global__ void k_rep_node(const bf16* __restrict__ preWbf, bf16* __restrict__ Wnode)
{
    int i = blockIdx.x * 256 + threadIdx.x;   // 3*1024*128
    int l = i >> 17, rem = i & 131071;
    int r = rem >> 7, c = rem & 127;
    bf16 v = (r < 512) ? preWbf[(size_t)l * 196608 + (size_t)r * 384 + c]
                       : preWbf[(size_t)l * 196608 + (size_t)(r - 512) * 384 + 128 + c];
    Wnode[i] = v;
}

__global__ void k_rep_em1(const bf16* __restrict__ em1Wbf, bf16* __restrict__ Wem1)
{
    int i = blockIdx.x * 256 + threadIdx.x;   // 512*128
    int r = i >> 7, c = i & 127;
    bf16 v = (r < 256) ? em1Wbf[(size_t)r * 256 + c]
                       : em1Wbf[(size_t)(r - 256) * 256 + 128 + c];
    Wem1[i] = v;
}

__global__ void k_ext_em1b(const float* __restrict__ em1b, float* __restrict__ ext)
{
    int i = blockIdx.x * 256 + threadIdx.x;   // 512
    ext[i] = (i < 256) ? em1b[i] : 0.f;
}

// ----------------------- CSR build -----------------------------------------
__global__ void k_count(const int* __restrict__ dst, int* __restrict__ counts)
{
    int e = blockIdx.x * 256 + threadIdx.x;
    atomicAdd(&counts[dst[e]], 1);
}

__global__ __launch_bounds__(1024) void k_scan(
    const int* __restrict__ counts, int* __restrict__ offs, int* __restrict__ cursor)
{
    __shared__ int ls[1024];
    int tid = threadIdx.x, base = tid * 4;
    int c0 = counts[base], c1 = counts[base + 1], c2 = counts[base + 2], c3 = counts[base + 3];
    ls[tid] = c0 + c1 + c2 + c3;
    __syncthreads();
    for (int d = 1; d < 1024; d <<= 1) {
        int v = (tid >= d) ? ls[tid - d] : 0;
        __syncthreads();
        ls[tid] += v;
        __syncthreads();
    }
    int r = tid ? ls[tid - 1] : 0;
    offs[base] = r;     cursor[base] = r;     r += c0;
    offs[base + 1] = r; cursor[base + 1] = r; r += c1;
    offs[base + 2] = r; cursor[base + 2] = r; r += c2;
    offs[base + 3] = r; cursor[base + 3] = r; r += c3;
    if (tid == 1023) offs[4096] = r;
}

__global__ void k_fill(const int* __restrict__ dst, const int* __restrict__ srcW,
                       int* __restrict__ cursor, int* __restrict__ pos,
                       int* __restrict__ srcord)
{
    int e = blockIdx.x * 256 + threadIdx.x;
    int p = atomicAdd(&cursor[dst[e]], 1);
    pos[e] = p;
    srcord[p] = srcW[e];
}

// ---------------------------------------------------------------------------
// Single-pass aggregation; outputs bf16 (postg casts to bf16 anyway —
// identical rounding point, halves agg-buffer HBM traffic both directions)
// ---------------------------------------------------------------------------
__global__ __launch_bounds__(128) void k_agg(
    const float* __restrict__ PdPs, const bf16* __restrict__ Qord,
    const int* __restrict__ srcord, const int* __restrict__ offs,
    bf16* __restrict__ aggX, bf16* __restrict__ aggS, bf16* __restrict__ aggM)
{
    int n = blockIdx.x, tid = threadIdx.x;
    int c = tid * 4;
    float4 pd = *(const float4*)(PdPs + (size_t)n * 1024 + c);
    float s0 = 0, s1 = 0, s2 = 0, s3 = 0;
    float q0 = 0, q1 = 0, q2 = 0, q3 = 0;
    float x0 = -3e38f, x1 = -3e38f, x2 = -3e38f, x3 = -3e38f;
    int beg = offs[n], end = offs[n + 1];
    for (int i = beg; i < end; i++) {
        int sn = srcord[i];
        float4 ps = *(const float4*)(PdPs + (size_t)sn * 1024 + 512 + c);
        bf16x4 qv = *(const bf16x4*)(Qord + (size_t)i * 512 + c);
        float m0 = pd.x + ps.x + (float)qv[0];
        float m1 = pd.y + ps.y + (float)qv[1];
        float m2 = pd.z + ps.z + (float)qv[2];
        float m3 = pd.w + ps.w + (float)qv[3];
        s0 += m0; s1 += m1; s2 += m2; s3 += m3;
        q0 += m0 * m0; q1 += m1 * m1; q2 += m2 * m2; q3 += m3 * m3;
        x0 = fmaxf(x0, m0); x1 = fmaxf(x1, m1); x2 = fmaxf(x2, m2); x3 = fmaxf(x3, m3);
    }
    int cnt = end - beg;
    float inv = 1.f / fmaxf((float)cnt, 1.f);
    float me0 = s0 * inv, me1 = s1 * inv, me2 = s2 * inv, me3 = s3 * inv;
    float v0 = fmaxf(q0 * inv - me0 * me0, 0.f);
    float v1 = fmaxf(q1 * inv - me1 * me1, 0.f);
    float v2 = fmaxf(q2 * inv - me2 * me2, 0.f);
    float v3 = fmaxf(q3 * inv - me3 * me3, 0.f);
    size_t o = (size_t)n * 512 + c;
    bf16x4 mx, st, me;
    mx[0] = (bf16)(cnt > 0 ? x0 : 0.f); mx[1] = (bf16)(cnt > 0 ? x1 : 0.f);
    mx[2] = (bf16)(cnt > 0 ? x2 : 0.f); mx[3] = (bf16)(cnt > 0 ? x3 : 0.f);
    st[0] = (bf16)sqrtf(v0 + 1e-5f); st[1] = (bf16)sqrtf(v1 + 1e-5f);
    st[2] = (bf16)sqrtf(v2 + 1e-5f); st[3] = (bf16)sqrtf(v3 + 1e-5f);
    me[0] = (bf16)me0; me[1] = (bf16)me1; me[2] = (bf16)me2; me[3] = (bf16)me3;
    *(bf16x4*)(aggX + o) = mx;
    *(bf16x4*)(aggS + o) = st;
    *(bf16x4*)(aggM + o) = me;
}

// --------------------------- GRU elementwise --------------------------------
// fo != nullptr on the final layer: writes out directly into d_out (both the
// leading and trailing out-copies), eliminating k_writeout entirely.
__global__ void k_gru(const float* __restrict__ gi, const float* __restrict__ gh,
                      float* __restrict__ hst, bf16* __restrict__ ob,
                      float* __restrict__ fo)
{
    int i = blockIdx.x * 256 + threadIdx.x;
    int k = i & 127;
    size_t b = (size_t)(i >> 7) * 384;
    float ir = gi[b + k],       hr = gh[b + k];
    float iz = gi[b + 128 + k], hz = gh[b + 128 + k];
    float ic = gi[b + 256 + k], hc = gh[b + 256 + k];
    float r = 1.f / (1.f + __expf(-(ir + hr)));
    float z = 1.f / (1.f + __expf(-(iz + hz)));
    float c = tanhf(ic + r * hc);
    float h = hst[i];
    float hn = (1.f - z) * c + z * h;
    hst[i] = hn;
    ob[i] = (bf16)hn;
    if (fo) { fo[i] = hn; fo[4718592 + i] = hn; }
}

__global__ void k_sentinel(float* __restrict__ o, float v)
{
    int i = blockIdx.x * 256 + threadIdx.x;
    o[i] = v;
}

// ===========================================================================
extern "C" void kernel_launch(void* const* d_in, const int* in_sizes, int n_in,
                              void* d_out, int out_size, void* d_ws, size_t ws_size,
                              hipStream_t stream)
{
    static const int exp_sizes[23] = {
        524288, 4194304, 131072, 24576, 384, 589824, 1536, 196608, 384,
        49152, 384, 49152, 49152, 384, 384, 65536, 256, 32768, 128,
        24576, 128, 8192, 64 };
    if (n_in != 23) { k_sentinel<<<2048, 256, 0, stream>>>((float*)d_out, 200.f); return; }
    for (int i = 0; i < 23; i++)
        if (in_sizes[i] != exp_sizes[i]) {
            k_sentinel<<<2048, 256, 0, stream>>>((float*)d_out, 60.f + 4.f * i);
            return;
        }
    if (out_size != 5242880) { k_sentinel<<<2048, 256, 0, stream>>>((float*)d_out, 52.f); return; }

    const int* eidx = (const int*)d_in[2];

    char* w = (char*)d_ws;
    size_t off = 0;
    auto alloc = [&](size_t bytes) -> char* {
        char* p = w + off;
        off = (off + bytes + 255) & ~(size_t)255;
        return p;
    };
    int*   dflag   = (int*)  alloc(256);
    int*   iflag   = (int*)  alloc(256);
    int*   srcW    = (int*)  alloc((size_t)EE * 4);
    int*   dstW    = (int*)  alloc((size_t)EE * 4);
    int*   pos     = (int*)  alloc((size_t)EE * 4);
    int*   srcord  = (int*)  alloc((size_t)EE * 4);
    float* out_f32 = (float*)alloc((size_t)NN * HH * 4);
    bf16*  out_bf  = (bf16*) alloc((size_t)NN * HH * 2);
    bf16*  m_bf    = (bf16*) alloc((size_t)NN * HH * 2);
    bf16*  ybf     = (bf16*) alloc((size_t)NN * HH * 2);
    bf16*  eaord   = (bf16*) alloc((size_t)EE * EDD * 2);
    bf16*  wcombBf = (bf16*) alloc((size_t)THD * EDD * 2);
    float* bcombx  = (float*)alloc((size_t)1024 * 4);
    int*   counts  = (int*)  alloc((size_t)NN * 4);
    int*   offs    = (int*)  alloc((size_t)(NN + 1) * 4);
    int*   cursor  = (int*)  alloc((size_t)NN * 4);
    float* PdPs    = (float*)alloc((size_t)NN * 1024 * 4);
    bf16*  aggX    = (bf16*) alloc((size_t)NN * THD * 2);
    bf16*  aggS    = (bf16*) alloc((size_t)NN * THD * 2);
    bf16*  aggM    = (bf16*) alloc((size_t)NN * THD * 2);
    float* encWc  = (float*)alloc((size_t)24576 * 4);
    float* encbc  = (float*)alloc((size_t)384 * 4);
    float* preWc  = (float*)alloc((size_t)589824 * 4);
    float* prebc  = (float*)alloc((size_t)1536 * 4);
    float* postbc = (float*)alloc((size_t)384 * 4);
    float* linbc  = (float*)alloc((size_t)384 * 4);
    float* bihc   = (float*)alloc((size_t)384 * 4);
    float* bhhc   = (float*)alloc((size_t)384 * 4);
    float* em1bc  = (float*)alloc((size_t)256 * 4);
    float* em1ext = (float*)alloc((size_t)512 * 4);
    float* em2bc  = (float*)alloc((size_t)128 * 4);
    float* eu1bc  = (float*)alloc((size_t)128 * 4);
    float* eu2bc  = (float*)alloc((size_t)64 * 4);
    bf16* preWbf = (bf16*)alloc((size_t)589824 * 2);
    bf16* WnodeBf= (bf16*)alloc((size_t)3 * 131072 * 2);
    bf16* postWbf= (bf16*)alloc((size_t)196608 * 2);
    bf16* linWbf = (bf16*)alloc((size_t)49152 * 2);
    bf16* WihBf  = (bf16*)alloc((size_t)49152 * 2);
    bf16* WhhBf  = (bf16*)alloc((size_t)49152 * 2);
    bf16* em1Wbf = (bf16*)alloc((size_t)65536 * 2);
    bf16* Wem1Bf = (bf16*)alloc((size_t)65536 * 2);
    bf16* em2Wbf = (bf16*)alloc((size_t)32768 * 2);
    bf16* eu1Wbf = (bf16*)alloc((size_t)24576 * 2);
    bf16* eu2Wbf = (bf16*)alloc((size_t)8192 * 2);
    // phase-shared region: Q_ord (PNA) / gi,gh (GRU) / SAB (edge)
    char* region = alloc((size_t)EE * 512 * 2);     // 67.1 MB
    bf16*  Qord = (bf16*) (region);
    float* gi   = (float*)(region);
    float* gh   = (float*)(region + 6291456);
    float* SAB  = (float*)(region);                 // [N,512] f32

    if (ws_size < off) { k_sentinel<<<2048, 256, 0, stream>>>((float*)d_out, 44.f); return; }

    // ---- index canonicalize + CSR ----
    k_detidx<<<1, 64, 0, stream>>>(eidx, iflag);
    k_extidx<<<EE / 256, 256, 0, stream>>>(eidx, srcW, dstW, iflag);
    hipMemsetAsync(counts, 0, NN * 4, stream);
    k_count<<<EE / 256, 256, 0, stream>>>(dstW, counts);
    k_scan<<<1, 1024, 0, stream>>>(counts, offs, cursor);
    k_fill<<<EE / 256, 256, 0, stream>>>(dstW, srcW, cursor, pos, srcord);

    // ---- float canonicalize ----
    k_detect<<<1, 64, 0, stream>>>(d_in[1], dflag);
    auto CF = [&](int idx, float* dst, int n) {
        k_canon_f<<<(n + 255) / 256, 256, 0, stream>>>(d_in[idx], dst, n, dflag);
    };
    auto CB = [&](int idx, bf16* dst, int n) {
        k_canon_b<<<(n + 255) / 256, 256, 0, stream>>>(d_in[idx], dst, n, dflag);
    };
    k_canon_fb<<<(NN * HH + 255) / 256, 256, 0, stream>>>(d_in[0], out_f32, out_bf, NN * HH, dflag);
    k_canon_ea<<<(EE * EDD + 255) / 256, 256, 0, stream>>>(d_in[1], eaord, pos, dflag);
    k_canon_fb<<<(589824 + 255) / 256, 256, 0, stream>>>(d_in[5], preWc, preWbf, 589824, dflag);
    CF(3, encWc, 24576);   CF(4, encbc, 384);   CF(6, prebc, 1536);
    CF(8, postbc, 384);    CF(10, linbc, 384);  CF(13, bihc, 384);  CF(14, bhhc, 384);
    CF(16, em1bc, 256);    CF(18, em2bc, 128);  CF(20, eu1bc, 128); CF(22, eu2bc, 64);
    CB(7, postWbf, 196608); CB(9, linWbf, 49152);
    CB(11, WihBf, 49152);   CB(12, WhhBf, 49152);
    CB(15, em1Wbf, 65536);  CB(17, em2Wbf, 32768);
    CB(19, eu1Wbf, 24576);  CB(21, eu2Wbf, 8192);
    // repacks
    k_rep_node<<<(3 * 131072) / 256, 256, 0, stream>>>(preWbf, WnodeBf);
    k_rep_em1<<<65536 / 256, 256, 0, stream>>>(em1Wbf, Wem1Bf);
    k_ext_em1b<<<2, 256, 0, stream>>>(em1bc, em1ext);

    auto GEMM = [&](const bf16* A, int lda, const bf16* Wm, int ldw, const float* bias,
                    void* C, int ldc, int M, int Nout, int K, bool relu, int om) {
        dim3 grid(M / 64, Nout / 64);
        if (relu) {
            if (om) k_mgemm<true, 1><<<grid, 256, 0, stream>>>(A, lda, Wm, ldw, bias, C, ldc, K);
            else    k_mgemm<true, 0><<<grid, 256, 0, stream>>>(A, lda, Wm, ldw, bias, C, ldc, K);
        } else {
            if (om) k_mgemm<false, 1><<<grid, 256, 0, stream>>>(A, lda, Wm, ldw, bias, C, ldc, K);
            else    k_mgemm<false, 0><<<grid, 256, 0, stream>>>(A, lda, Wm, ldw, bias, C, ldc, K);
        }
    };

    for (int l = 0; l < 3; l++) {
        const float* preW_l  = preWc  + (size_t)l * 196608;
        const float* encW_l  = encWc  + (size_t)l * 8192;
        const float* encb_l  = encbc  + (size_t)l * 128;
        const float* preb_l  = prebc  + (size_t)l * 512;
        const bf16*  Wnode_l = WnodeBf + (size_t)l * 131072;
        const bf16*  postW_l = postWbf + (size_t)l * 65536;
        const float* postb_l = postbc + (size_t)l * 128;
        const bf16*  linW_l  = linWbf + (size_t)l * 16384;
        const float* linb_l  = linbc  + (size_t)l * 128;
        const bool last = (l == 2);

        // ---- PNA ----
        k_wcomb<<<THD, 64, 0, stream>>>(preW_l, encW_l, encb_l, preb_l, wcombBf, bcombx);
        GEMM(out_bf, HH, Wnode_l, 128, bcombx, PdPs, 1024, NN, 1024, HH, false, 0);
        k_qgemm<<<dim3(EE / 64, 2), 256, 0, stream>>>(eaord, wcombBf, Qord);
        k_agg<<<NN, 128, 0, stream>>>(PdPs, Qord, srcord, offs, aggX, aggS, aggM);
        k_postg<<<dim3(NN / 64, 4), 256, 0, stream>>>(out_bf, aggX, aggS, aggM,
                                                      postW_l, postb_l, ybf);
        GEMM(ybf, HH, linW_l, HH, linb_l, m_bf, HH, NN, HH, HH, true, 1);
        // ---- GRU ----
        GEMM(m_bf,   HH, WihBf, HH, bihc, gi, 384, NN, 384, HH, false, 0);
        GEMM(out_bf, HH, WhhBf, HH, bhhc, gh, 384, NN, 384, HH, false, 0);
        k_gru<<<NN * HH / 256, 256, 0, stream>>>(gi, gh, out_f32, out_bf,
                                                 last ? (float*)d_out : (float*)nullptr);
        // ---- edge update (merged SAB + fused chain) ----
        GEMM(out_bf, HH, Wem1Bf, 128, em1ext, SAB, 512, NN, 512, HH, false, 0);
        k_edge<<<EE / 64, 256, 0, stream>>>(SAB, em2Wbf, em2bc, eu1Wbf, eu1bc,
                                            eu2Wbf, eu2bc, srcW, dstW, pos,
                                            eaord, last ? (float*)d_out + 524288 : (float*)nullptr);
    }
}

// Round 4
// 539.728 us; speedup vs baseline: 1.1978x; 1.0515x over previous
//
#include <hip/hip_runtime.h>
#include <hip/hip_bf16.h>
#include <math.h>

#define NN 4096
#define EE 65536
#define HH 128
#define EDD 64
#define THD 512

typedef __bf16 bf16;
typedef __bf16 bf16x8 __attribute__((ext_vector_type(8)));
typedef __bf16 bf16x4 __attribute__((ext_vector_type(4)));
typedef float  floatx4 __attribute__((ext_vector_type(4)));

// ---------------------------------------------------------------------------
// input dtype detects (proven: floats f32, edge_index int32; cheap insurance)
// ---------------------------------------------------------------------------
__global__ __launch_bounds__(64) void k_detect(const void* __restrict__ p,
                                               int* __restrict__ flag)
{
    const bf16* b = (const bf16*)p;
    int t = threadIdx.x;
    int bad = 0;
    for (int i = 0; i < 32; i++) {
        float v = (float)b[t * 32 + i];
        if (!(v == v) || fabsf(v) > 100.f) bad = 1;
    }
    unsigned long long m = __ballot(bad);
    if (t == 0) *flag = (m == 0ULL) ? 1 : 0;
}

__global__ void k_canon_f(const void* __restrict__ src, float* __restrict__ dst,
                          int n, const int* __restrict__ flag)
{
    int i = blockIdx.x * 256 + threadIdx.x;
    if (i >= n) return;
    dst[i] = (*flag) ? (float)((const bf16*)src)[i] : ((const float*)src)[i];
}

__global__ void k_canon_b(const void* __restrict__ src, bf16* __restrict__ dst,
                          int n, const int* __restrict__ flag)
{
    int i = blockIdx.x * 256 + threadIdx.x;
    if (i >= n) return;
    dst[i] = (*flag) ? ((const bf16*)src)[i] : (bf16)((const float*)src)[i];
}

__global__ void k_canon_fb(const void* __restrict__ src, float* __restrict__ dst,
                           bf16* __restrict__ dst2, int n, const int* __restrict__ flag)
{
    int i = blockIdx.x * 256 + threadIdx.x;
    if (i >= n) return;
    float v = (*flag) ? (float)((const bf16*)src)[i] : ((const float*)src)[i];
    dst[i] = v;
    dst2[i] = (bf16)v;
}

// ea canon: CSR-ordered bf16 only (f32 ea only needed as FINAL output,
// written directly to d_out by layer-3 k_edge)
__global__ void k_canon_ea(const void* __restrict__ src,
                           bf16* __restrict__ eaord, const int* __restrict__ pos,
                           const int* __restrict__ flag)
{
    int i = blockIdx.x * 256 + threadIdx.x;   // E*64
    int e = i >> 6, d = i & 63;
    float v = (*flag) ? (float)((const bf16*)src)[i] : ((const float*)src)[i];
    eaord[(size_t)pos[e] * 64 + d] = (bf16)v;
}

__global__ __launch_bounds__(64) void k_detidx(const int* __restrict__ p,
                                               int* __restrict__ iflag)
{
    int t = threadIdx.x;
    int bad = 0;
    for (int i = 0; i < 8; i++) {
        int k = t * 8 + i;
        int lo = p[2 * k], hi = p[2 * k + 1];
        if (hi != 0 || lo < 0 || lo >= NN) bad = 1;
    }
    unsigned long long m = __ballot(bad);
    if (t == 0) *iflag = (m == 0ULL) ? 1 : 0;
}

__global__ void k_extidx(const int* __restrict__ p, int* __restrict__ srcW,
                         int* __restrict__ dstW, const int* __restrict__ iflag)
{
    int e = blockIdx.x * 256 + threadIdx.x;
    int s, d;
    if (*iflag) { s = p[2 * e];  d = p[2 * EE + 2 * e]; }
    else        { s = p[e];      d = p[EE + e]; }
    srcW[e] = min(max(s, 0), NN - 1);
    dstW[e] = min(max(d, 0), NN - 1);
}

// ---------------------------------------------------------------------------
// MFMA bf16 GEMM (validated): C[M,Nout] = act(A @ W^T + bias)
// ---------------------------------------------------------------------------
template<bool RELU, int OM>
__global__ __launch_bounds__(256) void k_mgemm(
    const bf16* __restrict__ A, int lda,
    const bf16* __restrict__ W, int ldw, const float* __restrict__ bias,
    void* __restrict__ Cv, int ldc, int K)
{
    __shared__ bf16 As[64][40];
    __shared__ bf16 Ws[64][40];
    const int m0 = blockIdx.x * 64, n0 = blockIdx.y * 64;
    const int tid = threadIdx.x, wave = tid >> 6, lane = tid & 63;
    const int wm = (wave & 1) * 32, wn = (wave >> 1) * 32;
    const int lrow = tid >> 2, lcol = (tid & 3) * 8;
    const int fr = lane & 15, fk = (lane >> 4) * 8;
    floatx4 acc00 = {0,0,0,0}, acc01 = {0,0,0,0}, acc10 = {0,0,0,0}, acc11 = {0,0,0,0};

    for (int k0 = 0; k0 < K; k0 += 32) {
        bf16x8 av = *(const bf16x8*)(A + (size_t)(m0 + lrow) * lda + k0 + lcol);
        bf16x8 wv = *(const bf16x8*)(W + (size_t)(n0 + lrow) * ldw + k0 + lcol);
        __syncthreads();
        *(bf16x8*)&As[lrow][lcol] = av;
        *(bf16x8*)&Ws[lrow][lcol] = wv;
        __syncthreads();
        bf16x8 a0 = *(const bf16x8*)&As[wm + fr][fk];
        bf16x8 a1 = *(const bf16x8*)&As[wm + 16 + fr][fk];
        bf16x8 b0 = *(const bf16x8*)&Ws[wn + fr][fk];
        bf16x8 b1 = *(const bf16x8*)&Ws[wn + 16 + fr][fk];
        acc00 = __builtin_amdgcn_mfma_f32_16x16x32_bf16(a0, b0, acc00, 0, 0, 0);
        acc01 = __builtin_amdgcn_mfma_f32_16x16x32_bf16(a0, b1, acc01, 0, 0, 0);
        acc10 = __builtin_amdgcn_mfma_f32_16x16x32_bf16(a1, b0, acc10, 0, 0, 0);
        acc11 = __builtin_amdgcn_mfma_f32_16x16x32_bf16(a1, b1, acc11, 0, 0, 0);
    }
    const int cc = lane & 15, cr = (lane >> 4) * 4;
    float vb0 = bias ? bias[n0 + wn + cc] : 0.f;
    float vb1 = bias ? bias[n0 + wn + 16 + cc] : 0.f;
    floatx4 accs[2][2] = {{acc00, acc01}, {acc10, acc11}};
#pragma unroll
    for (int mt = 0; mt < 2; mt++)
#pragma unroll
        for (int nt = 0; nt < 2; nt++) {
            float vb = nt ? vb1 : vb0;
#pragma unroll
            for (int i = 0; i < 4; i++) {
                int gm = m0 + wm + mt * 16 + cr + i;
                int gn = n0 + wn + nt * 16 + cc;
                float v = accs[mt][nt][i] + vb;
                if (RELU) v = fmaxf(v, 0.f);
                if (OM == 1) ((bf16*)Cv)[(size_t)gm * ldc + gn] = (bf16)v;
                else         ((float*)Cv)[(size_t)gm * ldc + gn] = v;
            }
        }
}

// ---------------------------------------------------------------------------
// Q GEMM, wide tile: Q_ord[E,512] = eaord[E,64] @ wcomb[512,64]^T
// ---------------------------------------------------------------------------
__global__ __launch_bounds__(256) void k_qgemm(
    const bf16* __restrict__ eaord, const bf16* __restrict__ wcomb,
    bf16* __restrict__ Qord)
{
    __shared__ bf16 As[64][72];
    __shared__ bf16 Ws[256][72];
    const int e0 = blockIdx.x * 64, n0g = blockIdx.y * 256;
    const int tid = threadIdx.x, wave = tid >> 6, lane = tid & 63;
    const int fr = lane & 15, fk = (lane >> 4) * 8;
    const int cc = lane & 15, cr = (lane >> 4) * 4;

#pragma unroll
    for (int v = 0; v < 2; v++) {
        int lin = v * 2048 + tid * 8;
        int r = lin >> 6, c = lin & 63;
        *(bf16x8*)&As[r][c] = *(const bf16x8*)(eaord + (size_t)(e0 + r) * 64 + c);
    }
#pragma unroll
    for (int v = 0; v < 8; v++) {
        int lin = v * 2048 + tid * 8;
        int r = lin >> 6, c = lin & 63;
        *(bf16x8*)&Ws[r][c] = *(const bf16x8*)(wcomb + (size_t)(n0g + r) * 64 + c);
    }
    __syncthreads();

    floatx4 acc[4][4];
#pragma unroll
    for (int mt = 0; mt < 4; mt++)
#pragma unroll
        for (int nt = 0; nt < 4; nt++) acc[mt][nt] = (floatx4){0,0,0,0};

#pragma unroll
    for (int kk = 0; kk < 64; kk += 32) {
        bf16x8 af[4], bv[4];
#pragma unroll
        for (int mt = 0; mt < 4; mt++) af[mt] = *(const bf16x8*)&As[mt * 16 + fr][kk + fk];
#pragma unroll
        for (int nt = 0; nt < 4; nt++) bv[nt] = *(const bf16x8*)&Ws[wave * 64 + nt * 16 + fr][kk + fk];
#pragma unroll
        for (int mt = 0; mt < 4; mt++)
#pragma unroll
            for (int nt = 0; nt < 4; nt++)
                acc[mt][nt] = __builtin_amdgcn_mfma_f32_16x16x32_bf16(af[mt], bv[nt], acc[mt][nt], 0, 0, 0);
    }
#pragma unroll
    for (int mt = 0; mt < 4; mt++)
#pragma unroll
        for (int nt = 0; nt < 4; nt++)
#pragma unroll
            for (int i = 0; i < 4; i++) {
                int row = mt * 16 + cr + i;
                int col = n0g + wave * 64 + nt * 16 + cc;
                Qord[(size_t)(e0 + row) * 512 + col] = (bf16)acc[mt][nt][i];
            }
}

// ---------------------------------------------------------------------------
// Fused edge update — R3-proven structure (per-k-step A gather + LDS weight
// staging), upgraded: SAB is bf16 (4.2 MB → ~L2-resident per XCD; half the
// gather bytes) and BK=64 (9 k-steps / 18 barriers, was 18 / 36; 16 MFMAs
// per barrier pair). LDS 61440 B → 2 blocks/CU (grid-limited anyway).
// ---------------------------------------------------------------------------
__global__ __launch_bounds__(256) void k_edge(
    const bf16* __restrict__ SAB,
    const bf16* __restrict__ em2W, const float* __restrict__ em2b,
    const bf16* __restrict__ eu1W, const float* __restrict__ eu1b,
    const bf16* __restrict__ eu2W, const float* __restrict__ eu2b,
    const int* __restrict__ src, const int* __restrict__ dst,
    const int* __restrict__ pos,
    bf16* __restrict__ eaord, float* __restrict__ ea_out_f)
{
    __shared__ char smem[61440];
    bf16 (*Ws)[72]   = (bf16 (*)[72])smem;                 // 128x72 = 18432 B
    bf16 (*med)[200] = (bf16 (*)[200])(smem + 18432);      // 64x200 = 25600 B
    bf16 (*As)[72]   = (bf16 (*)[72])(smem + 44032);       // 64x72 = 9216 B (stage 1; aliases t2s)
    bf16 (*t2s)[136] = (bf16 (*)[136])(smem + 44032);      // 64x136 = 17408 B (stages 2-3)

    const int e0 = blockIdx.x * 64;
    const int tid = threadIdx.x, wave = tid >> 6, lane = tid & 63;
    const int arow = tid >> 2, ac16 = (tid & 3) * 16;      // A loader: 64 rows x 4x16 cols
    const int fr = lane & 15, fk = (lane >> 4) * 8;
    const int cc = lane & 15, cr = (lane >> 4) * 4;
    const int sI = src[e0 + arow], dI = dst[e0 + arow];
    const floatx4 z4 = {0.f, 0.f, 0.f, 0.f};

    // ---------- stage 1: m_ed = relu(A @ em2W^T + em2b)  [64x128, K=256, BK=64] ----------
    const int wm1 = (wave & 1) * 32, wn1 = (wave >> 1) * 64;
    floatx4 acc1[2][4];
#pragma unroll
    for (int mt = 0; mt < 2; mt++)
#pragma unroll
        for (int nt = 0; nt < 4; nt++) acc1[mt][nt] = z4;

    for (int k0 = 0; k0 < 256; k0 += 64) {
        // A slice: relu(SAB[sI][k0+ac16..+15] + SAB[dI][256+k0+ac16..+15]) — bf16x8 loads
        const bf16* ps = SAB + (size_t)sI * 512 + k0 + ac16;
        const bf16* pq = SAB + (size_t)dI * 512 + 256 + k0 + ac16;
        bf16x8 s0 = *(const bf16x8*)ps, s1 = *(const bf16x8*)(ps + 8);
        bf16x8 d0 = *(const bf16x8*)pq, d1 = *(const bf16x8*)(pq + 8);
        bf16 a16[16];
#pragma unroll
        for (int j = 0; j < 8; j++) {
            a16[j]     = (bf16)fmaxf((float)s0[j] + (float)d0[j], 0.f);
            a16[j + 8] = (bf16)fmaxf((float)s1[j] + (float)d1[j], 0.f);
        }
        // W slice: 128 rows x 64 cols, 4 bf16x8 per thread
        int wr = tid & 127, wc = (tid >> 7) * 32;
        bf16x8 w0 = *(const bf16x8*)(em2W + (size_t)wr * 256 + k0 + wc);
        bf16x8 w1 = *(const bf16x8*)(em2W + (size_t)wr * 256 + k0 + wc + 8);
        bf16x8 w2 = *(const bf16x8*)(em2W + (size_t)wr * 256 + k0 + wc + 16);
        bf16x8 w3 = *(const bf16x8*)(em2W + (size_t)wr * 256 + k0 + wc + 24);
        __syncthreads();
        *(bf16x8*)&As[arow][ac16]     = *(bf16x8*)&a16[0];
        *(bf16x8*)&As[arow][ac16 + 8] = *(bf16x8*)&a16[8];
        *(bf16x8*)&Ws[wr][wc]      = w0;
        *(bf16x8*)&Ws[wr][wc + 8]  = w1;
        *(bf16x8*)&Ws[wr][wc + 16] = w2;
        *(bf16x8*)&Ws[wr][wc + 24] = w3;
        __syncthreads();
#pragma unroll
        for (int kk = 0; kk < 64; kk += 32) {
            bf16x8 af[2], bv[4];
            af[0] = *(const bf16x8*)&As[wm1 + fr][kk + fk];
            af[1] = *(const bf16x8*)&As[wm1 + 16 + fr][kk + fk];
#pragma unroll
            for (int nt = 0; nt < 4; nt++) bv[nt] = *(const bf16x8*)&Ws[wn1 + nt * 16 + fr][kk + fk];
#pragma unroll
            for (int mt = 0; mt < 2; mt++)
#pragma unroll
                for (int nt = 0; nt < 4; nt++)
                    acc1[mt][nt] = __builtin_amdgcn_mfma_f32_16x16x32_bf16(af[mt], bv[nt], acc1[mt][nt], 0, 0, 0);
        }
    }
    // med region is disjoint from As/Ws — no barrier needed before these writes
#pragma unroll
    for (int mt = 0; mt < 2; mt++)
#pragma unroll
        for (int nt = 0; nt < 4; nt++)
#pragma unroll
            for (int i = 0; i < 4; i++) {
                int row = wm1 + mt * 16 + cr + i;
                int col = wn1 + nt * 16 + cc;
                med[row][col] = (bf16)fmaxf(acc1[mt][nt][i] + em2b[col], 0.f);
            }
    // append ea tile (CSR-ordered rows via pos)
    {
        int r = tid >> 2, c0 = (tid & 3) * 16;
        int pr = pos[e0 + r];
        *(bf16x8*)&med[r][128 + c0]     = *(const bf16x8*)(eaord + (size_t)pr * 64 + c0);
        *(bf16x8*)&med[r][128 + c0 + 8] = *(const bf16x8*)(eaord + (size_t)pr * 64 + c0 + 8);
    }
    // med-ready sync provided by stage-2's first in-loop barrier

    // ---------- stage 2: t2 = relu([m_ed|ea] @ eu1W^T + eu1b)  [64x128, K=192, BK=64] ----------
    floatx4 acc2[2][4];
#pragma unroll
    for (int mt = 0; mt < 2; mt++)
#pragma unroll
        for (int nt = 0; nt < 4; nt++) acc2[mt][nt] = z4;

    for (int k0 = 0; k0 < 192; k0 += 64) {
        int wr = tid & 127, wc = (tid >> 7) * 32;
        bf16x8 w0 = *(const bf16x8*)(eu1W + (size_t)wr * 192 + k0 + wc);
        bf16x8 w1 = *(const bf16x8*)(eu1W + (size_t)wr * 192 + k0 + wc + 8);
        bf16x8 w2 = *(const bf16x8*)(eu1W + (size_t)wr * 192 + k0 + wc + 16);
        bf16x8 w3 = *(const bf16x8*)(eu1W + (size_t)wr * 192 + k0 + wc + 24);
        __syncthreads();
        *(bf16x8*)&Ws[wr][wc]      = w0;
        *(bf16x8*)&Ws[wr][wc + 8]  = w1;
        *(bf16x8*)&Ws[wr][wc + 16] = w2;
        *(bf16x8*)&Ws[wr][wc + 24] = w3;
        __syncthreads();
#pragma unroll
        for (int kk = 0; kk < 64; kk += 32) {
            bf16x8 af[2], bv[4];
            af[0] = *(const bf16x8*)&med[wm1 + fr][k0 + kk + fk];
            af[1] = *(const bf16x8*)&med[wm1 + 16 + fr][k0 + kk + fk];
#pragma unroll
            for (int nt = 0; nt < 4; nt++) bv[nt] = *(const bf16x8*)&Ws[wn1 + nt * 16 + fr][kk + fk];
#pragma unroll
            for (int mt = 0; mt < 2; mt++)
#pragma unroll
                for (int nt = 0; nt < 4; nt++)
                    acc2[mt][nt] = __builtin_amdgcn_mfma_f32_16x16x32_bf16(af[mt], bv[nt], acc2[mt][nt], 0, 0, 0);
        }
    }
    // t2s aliases As (dead since end of stage 1, separated by stage-2 barriers);
    // disjoint from med and Ws — safe to write without an extra barrier
#pragma unroll
    for (int mt = 0; mt < 2; mt++)
#pragma unroll
        for (int nt = 0; nt < 4; nt++)
#pragma unroll
            for (int i = 0; i < 4; i++) {
                int row = wm1 + mt * 16 + cr + i;
                int col = wn1 + nt * 16 + cc;
                t2s[row][col] = (bf16)fmaxf(acc2[mt][nt][i] + eu1b[col], 0.f);
            }
    // t2s-ready sync provided by stage-3's first in-loop barrier

    // ---------- stage 3: ea' = t2 @ eu2W^T + eu2b  [64x64, K=128, BK=64] ----------
    const int wm3 = (wave & 1) * 32, wn3 = (wave >> 1) * 32;
    floatx4 acc3[2][2];
#pragma unroll
    for (int mt = 0; mt < 2; mt++)
#pragma unroll
        for (int nt = 0; nt < 2; nt++) acc3[mt][nt] = z4;

    for (int k0 = 0; k0 < 128; k0 += 64) {
        int wr = tid & 63, wc = (tid >> 6) * 16;
        bf16x8 w0 = *(const bf16x8*)(eu2W + (size_t)wr * 128 + k0 + wc);
        bf16x8 w1 = *(const bf16x8*)(eu2W + (size_t)wr * 128 + k0 + wc + 8);
        __syncthreads();
        *(bf16x8*)&Ws[wr][wc]     = w0;
        *(bf16x8*)&Ws[wr][wc + 8] = w1;
        __syncthreads();
#pragma unroll
        for (int kk = 0; kk < 64; kk += 32) {
            bf16x8 af[2], bv[2];
            af[0] = *(const bf16x8*)&t2s[wm3 + fr][k0 + kk + fk];
            af[1] = *(const bf16x8*)&t2s[wm3 + 16 + fr][k0 + kk + fk];
#pragma unroll
            for (int nt = 0; nt < 2; nt++) bv[nt] = *(const bf16x8*)&Ws[wn3 + nt * 16 + fr][kk + fk];
#pragma unroll
            for (int mt = 0; mt < 2; mt++)
#pragma unroll
                for (int nt = 0; nt < 2; nt++)
                    acc3[mt][nt] = __builtin_amdgcn_mfma_f32_16x16x32_bf16(af[mt], bv[nt], acc3[mt][nt], 0, 0, 0);
        }
    }
#pragma unroll
    for (int mt = 0; mt < 2; mt++)
#pragma unroll
        for (int nt = 0; nt < 2; nt++)
#pragma unroll
            for (int i = 0; i < 4; i++) {
                int row = wm3 + mt * 16 + cr + i;
                int col = wn3 + nt * 16 + cc;
                float v = acc3[mt][nt][i] + eu2b[col];
                int e = e0 + row;
                eaord[(size_t)pos[e] * 64 + col] = (bf16)v;
                if (ea_out_f) ea_out_f[(size_t)e * 64 + col] = v;  // final layer only
            }
}

// ---------------------------------------------------------------------------
// Post-MLP per-tower MFMA GEMM — consumes bf16 agg buffers (identical
// rounding point; vectorized bf16x8 loads)
// ---------------------------------------------------------------------------
__global__ __launch_bounds__(256) void k_postg(
    const bf16* __restrict__ xin, const bf16* __restrict__ aggX,
    const bf16* __restrict__ aggS, const bf16* __restrict__ aggM,
    const bf16* __restrict__ qWbf, const float* __restrict__ qb,
    bf16* __restrict__ ybf)
{
    __shared__ bf16 As[64][40];
    __shared__ bf16 Ws[32][40];
    const int n0 = blockIdx.x * 64, t = blockIdx.y;
    const int tid = threadIdx.x, wave = tid >> 6, lane = tid & 63;
    const int lrow = tid >> 2, lcol = (tid & 3) * 8;
    const int fr = lane & 15, fk = (lane >> 4) * 8;
    floatx4 acc0 = {0,0,0,0}, acc1 = {0,0,0,0};

    for (int k0 = 0; k0 < 512; k0 += 32) {
        int n = n0 + lrow;
        int c0 = k0 + lcol;
        const bf16* srcp;
        if (c0 < 128)      srcp = xin  + (size_t)n * 128 + c0;
        else if (c0 < 256) srcp = aggX + (size_t)n * 512 + t * 128 + (c0 - 128);
        else if (c0 < 384) srcp = aggS + (size_t)n * 512 + t * 128 + (c0 - 256);
        else               srcp = aggM + (size_t)n * 512 + t * 128 + (c0 - 384);
        bf16x8 a8 = *(const bf16x8*)srcp;
        bf16 w8[8];
        if (tid < 128) {
            int wr = tid >> 2, wc = (tid & 3) * 8;
            *(bf16x8*)w8 = *(const bf16x8*)(qWbf + (size_t)(t * 32 + wr) * 512 + k0 + wc);
        }
        __syncthreads();
        *(bf16x8*)&As[lrow][lcol] = a8;
        if (tid < 128) {
            int wr = tid >> 2, wc = (tid & 3) * 8;
            *(bf16x8*)&Ws[wr][wc] = *(bf16x8*)w8;
        }
        __syncthreads();
        bf16x8 a  = *(const bf16x8*)&As[wave * 16 + fr][fk];
        bf16x8 b0 = *(const bf16x8*)&Ws[fr][fk];
        bf16x8 b1 = *(const bf16x8*)&Ws[16 + fr][fk];
        acc0 = __builtin_amdgcn_mfma_f32_16x16x32_bf16(a, b0, acc0, 0, 0, 0);
        acc1 = __builtin_amdgcn_mfma_f32_16x16x32_bf16(a, b1, acc1, 0, 0, 0);
    }
    const int cc = lane & 15, cr = (lane >> 4) * 4;
#pragma unroll
    for (int i = 0; i < 4; i++) {
        int gn = n0 + wave * 16 + cr + i;
        ybf[(size_t)gn * 128 + t * 32 + cc]      = (bf16)(acc0[i] + qb[t * 32 + cc]);
        ybf[(size_t)gn * 128 + t * 32 + 16 + cc] = (bf16)(acc1[i] + qb[t * 32 + 16 + cc]);
    }
}

// ---------------------------------------------------------------------------
// Fold edge-encoder into pre-MLP; writes zero-extended bias [1024].
// ---------------------------------------------------------------------------
__global__ __launch_bounds__(64) void k_wcomb(
    const float* __restrict__ preW, const float* __restrict__ encW,
    const float* __restrict__ encb, const float* __restrict__ preb,
    bf16* __restrict__ wcomb, float* __restrict__ bcombext)
{
    int tf = blockIdx.x, d = threadIdx.x;
    __shared__ float pw[128];
    __shared__ float red[64];
    const float* pr = preW + (size_t)tf * 384 + 256;
    pw[d]      = pr[d];
    pw[d + 64] = pr[d + 64];
    __syncthreads();
    float acc = 0.f;
    for (int h = 0; h < 128; h++) acc += pw[h] * encW[h * 64 + d];
    wcomb[tf * 64 + d] = (bf16)acc;
    float b = pw[d] * encb[d] + pw[d + 64] * encb[d + 64];
    red[d] = b;
    __syncthreads();
    for (int s = 32; s > 0; s >>= 1) { if (d < s) red[d] += red[d + s]; __syncthreads(); }
    if (d == 0) {
        bcombext[tf] = red[0] + preb[tf];
        bcombext[512 + tf] = 0.f;
    }
}

// ---------------- weight repacks (once per launch) --------------------------
__global__ void k_rep_node(const bf16* __restrict__ preWbf, bf16* __restrict__ Wnode)
{
    int i = blockIdx.x * 256 + threadIdx.x;   // 3*1024*128
    int l = i >> 17, rem = i & 131071;
    int r = rem >> 7, c = rem & 127;
    bf16 v = (r < 512) ? preWbf[(size_t)l * 196608 + (size_t)r * 384 + c]
                       : preWbf[(size_t)l * 196608 + (size_t)(r - 512) * 384 + 128 + c];
    Wnode[i] = v;
}

__global__ void k_rep_em1(const bf16* __restrict__ em1Wbf, bf16* __restrict__ Wem1)
{
    int i = blockIdx.x * 256 + threadIdx.x;   // 512*128
    int r = i >> 7, c = i & 127;
    bf16 v = (r < 256) ? em1Wbf[(size_t)r * 256 + c]
                       : em1Wbf[(size_t)(r - 256) * 256 + 128 + c];
    Wem1[i] = v;
}

__global__ void k_ext_em1b(const float* __restrict__ em1b, float* __restrict__ ext)
{
    int i = blockIdx.x * 256 + threadIdx.x;   // 512
    ext[i] = (i < 256) ? em1b[i] : 0.f;
}

// ----------------------- CSR build -----------------------------------------
__global__ void k_count(const int* __restrict__ dst, int* __restrict__ counts)
{
    int e = blockIdx.x * 256 + threadIdx.x;
    atomicAdd(&counts[dst[e]], 1);
}

__global__ __launch_bounds__(1024) void k_scan(
    const int* __restrict__ counts, int* __restrict__ offs, int* __restrict__ cursor)
{
    __shared__ int ls[1024];
    int tid = threadIdx.x, base = tid * 4;
    int c0 = counts[base], c1 = counts[base + 1], c2 = counts[base + 2], c3 = counts[base + 3];
    ls[tid] = c0 + c1 + c2 + c3;
    __syncthreads();
    for (int d = 1; d < 1024; d <<= 1) {
        int v = (tid >= d) ? ls[tid - d] : 0;
        __syncthreads();
        ls[tid] += v;
        __syncthreads();
    }
    int r = tid ? ls[tid - 1] : 0;
    offs[base] = r;     cursor[base] = r;     r += c0;
    offs[base + 1] = r; cursor[base + 1] = r; r += c1;
    offs[base + 2] = r; cursor[base + 2] = r; r += c2;
    offs[base + 3] = r; cursor[base + 3] = r; r += c3;
    if (tid == 1023) offs[4096] = r;
}

__global__ void k_fill(const int* __restrict__ dst, const int* __restrict__ srcW,
                       int* __restrict__ cursor, int* __restrict__ pos,
                       int* __restrict__ srcord)
{
    int e = blockIdx.x * 256 + threadIdx.x;
    int p = atomicAdd(&cursor[dst[e]], 1);
    pos[e] = p;
    srcord[p] = srcW[e];
}

// ---------------------------------------------------------------------------
// Single-pass aggregation; outputs bf16 (postg casts to bf16 anyway —
// identical rounding point, halves agg-buffer HBM traffic both directions)
// ---------------------------------------------------------------------------
__global__ __launch_bounds__(128) void k_agg(
    const float* __restrict__ PdPs, const bf16* __restrict__ Qord,
    const int* __restrict__ srcord, const int* __restrict__ offs,
    bf16* __restrict__ aggX, bf16* __restrict__ aggS, bf16* __restrict__ aggM)
{
    int n = blockIdx.x, tid = threadIdx.x;
    int c = tid * 4;
    float4 pd = *(const float4*)(PdPs + (size_t)n * 1024 + c);
    float s0 = 0, s1 = 0, s2 = 0, s3 = 0;
    float q0 = 0, q1 = 0, q2 = 0, q3 = 0;
    float x0 = -3e38f, x1 = -3e38f, x2 = -3e38f, x3 = -3e38f;
    int beg = offs[n], end = offs[n + 1];
    for (int i = beg; i < end; i++) {
        int sn = srcord[i];
        float4 ps = *(const float4*)(PdPs + (size_t)sn * 1024 + 512 + c);
        bf16x4 qv = *(const bf16x4*)(Qord + (size_t)i * 512 + c);
        float m0 = pd.x + ps.x + (float)qv[0];
        float m1 = pd.y + ps.y + (float)qv[1];
        float m2 = pd.z + ps.z + (float)qv[2];
        float m3 = pd.w + ps.w + (float)qv[3];
        s0 += m0; s1 += m1; s2 += m2; s3 += m3;
        q0 += m0 * m0; q1 += m1 * m1; q2 += m2 * m2; q3 += m3 * m3;
        x0 = fmaxf(x0, m0); x1 = fmaxf(x1, m1); x2 = fmaxf(x2, m2); x3 = fmaxf(x3, m3);
    }
    int cnt = end - beg;
    float inv = 1.f / fmaxf((float)cnt, 1.f);
    float me0 = s0 * inv, me1 = s1 * inv, me2 = s2 * inv, me3 = s3 * inv;
    float v0 = fmaxf(q0 * inv - me0 * me0, 0.f);
    float v1 = fmaxf(q1 * inv - me1 * me1, 0.f);
    float v2 = fmaxf(q2 * inv - me2 * me2, 0.f);
    float v3 = fmaxf(q3 * inv - me3 * me3, 0.f);
    size_t o = (size_t)n * 512 + c;
    bf16x4 mx, st, me;
    mx[0] = (bf16)(cnt > 0 ? x0 : 0.f); mx[1] = (bf16)(cnt > 0 ? x1 : 0.f);
    mx[2] = (bf16)(cnt > 0 ? x2 : 0.f); mx[3] = (bf16)(cnt > 0 ? x3 : 0.f);
    st[0] = (bf16)sqrtf(v0 + 1e-5f); st[1] = (bf16)sqrtf(v1 + 1e-5f);
    st[2] = (bf16)sqrtf(v2 + 1e-5f); st[3] = (bf16)sqrtf(v3 + 1e-5f);
    me[0] = (bf16)me0; me[1] = (bf16)me1; me[2] = (bf16)me2; me[3] = (bf16)me3;
    *(bf16x4*)(aggX + o) = mx;
    *(bf16x4*)(aggS + o) = st;
    *(bf16x4*)(aggM + o) = me;
}

// --------------------------- GRU elementwise --------------------------------
// fo != nullptr on the final layer: writes out directly into d_out (both the
// leading and trailing out-copies), eliminating k_writeout entirely.
__global__ void k_gru(const float* __restrict__ gi, const float* __restrict__ gh,
                      float* __restrict__ hst, bf16* __restrict__ ob,
                      float* __restrict__ fo)
{
    int i = blockIdx.x * 256 + threadIdx.x;
    int k = i & 127;
    size_t b = (size_t)(i >> 7) * 384;
    float ir = gi[b + k],       hr = gh[b + k];
    float iz = gi[b + 128 + k], hz = gh[b + 128 + k];
    float ic = gi[b + 256 + k], hc = gh[b + 256 + k];
    float r = 1.f / (1.f + __expf(-(ir + hr)));
    float z = 1.f / (1.f + __expf(-(iz + hz)));
    float c = tanhf(ic + r * hc);
    float h = hst[i];
    float hn = (1.f - z) * c + z * h;
    hst[i] = hn;
    ob[i] = (bf16)hn;
    if (fo) { fo[i] = hn; fo[4718592 + i] = hn; }
}

__global__ void k_sentinel(float* __restrict__ o, float v)
{
    int i = blockIdx.x * 256 + threadIdx.x;
    o[i] = v;
}

// ===========================================================================
extern "C" void kernel_launch(void* const* d_in, const int* in_sizes, int n_in,
                              void* d_out, int out_size, void* d_ws, size_t ws_size,
                              hipStream_t stream)
{
    static const int exp_sizes[23] = {
        524288, 4194304, 131072, 24576, 384, 589824, 1536, 196608, 384,
        49152, 384, 49152, 49152, 384, 384, 65536, 256, 32768, 128,
        24576, 128, 8192, 64 };
    if (n_in != 23) { k_sentinel<<<2048, 256, 0, stream>>>((float*)d_out, 200.f); return; }
    for (int i = 0; i < 23; i++)
        if (in_sizes[i] != exp_sizes[i]) {
            k_sentinel<<<2048, 256, 0, stream>>>((float*)d_out, 60.f + 4.f * i);
            return;
        }
    if (out_size != 5242880) { k_sentinel<<<2048, 256, 0, stream>>>((float*)d_out, 52.f); return; }

    const int* eidx = (const int*)d_in[2];

    char* w = (char*)d_ws;
    size_t off = 0;
    auto alloc = [&](size_t bytes) -> char* {
        char* p = w + off;
        off = (off + bytes + 255) & ~(size_t)255;
        return p;
    };
    int*   dflag   = (int*)  alloc(256);
    int*   iflag   = (int*)  alloc(256);
    int*   srcW    = (int*)  alloc((size_t)EE * 4);
    int*   dstW    = (int*)  alloc((size_t)EE * 4);
    int*   pos     = (int*)  alloc((size_t)EE * 4);
    int*   srcord  = (int*)  alloc((size_t)EE * 4);
    float* out_f32 = (float*)alloc((size_t)NN * HH * 4);
    bf16*  out_bf  = (bf16*) alloc((size_t)NN * HH * 2);
    bf16*  m_bf    = (bf16*) alloc((size_t)NN * HH * 2);
    bf16*  ybf     = (bf16*) alloc((size_t)NN * HH * 2);
    bf16*  eaord   = (bf16*) alloc((size_t)EE * EDD * 2);
    bf16*  wcombBf = (bf16*) alloc((size_t)THD * EDD * 2);
    float* bcombx  = (float*)alloc((size_t)1024 * 4);
    int*   counts  = (int*)  alloc((size_t)NN * 4);
    int*   offs    = (int*)  alloc((size_t)(NN + 1) * 4);
    int*   cursor  = (int*)  alloc((size_t)NN * 4);
    float* PdPs    = (float*)alloc((size_t)NN * 1024 * 4);
    bf16*  aggX    = (bf16*) alloc((size_t)NN * THD * 2);
    bf16*  aggS    = (bf16*) alloc((size_t)NN * THD * 2);
    bf16*  aggM    = (bf16*) alloc((size_t)NN * THD * 2);
    float* encWc  = (float*)alloc((size_t)24576 * 4);
    float* encbc  = (float*)alloc((size_t)384 * 4);
    float* preWc  = (float*)alloc((size_t)589824 * 4);
    float* prebc  = (float*)alloc((size_t)1536 * 4);
    float* postbc = (float*)alloc((size_t)384 * 4);
    float* linbc  = (float*)alloc((size_t)384 * 4);
    float* bihc   = (float*)alloc((size_t)384 * 4);
    float* bhhc   = (float*)alloc((size_t)384 * 4);
    float* em1bc  = (float*)alloc((size_t)256 * 4);
    float* em1ext = (float*)alloc((size_t)512 * 4);
    float* em2bc  = (float*)alloc((size_t)128 * 4);
    float* eu1bc  = (float*)alloc((size_t)128 * 4);
    float* eu2bc  = (float*)alloc((size_t)64 * 4);
    bf16* preWbf = (bf16*)alloc((size_t)589824 * 2);
    bf16* WnodeBf= (bf16*)alloc((size_t)3 * 131072 * 2);
    bf16* postWbf= (bf16*)alloc((size_t)196608 * 2);
    bf16* linWbf = (bf16*)alloc((size_t)49152 * 2);
    bf16* WihBf  = (bf16*)alloc((size_t)49152 * 2);
    bf16* WhhBf  = (bf16*)alloc((size_t)49152 * 2);
    bf16* em1Wbf = (bf16*)alloc((size_t)65536 * 2);
    bf16* Wem1Bf = (bf16*)alloc((size_t)65536 * 2);
    bf16* em2Wbf = (bf16*)alloc((size_t)32768 * 2);
    bf16* eu1Wbf = (bf16*)alloc((size_t)24576 * 2);
    bf16* eu2Wbf = (bf16*)alloc((size_t)8192 * 2);
    // phase-shared region: Q_ord (PNA) / gi,gh (GRU) / SAB (edge, bf16)
    char* region = alloc((size_t)EE * 512 * 2);     // 67.1 MB
    bf16*  Qord = (bf16*) (region);
    float* gi   = (float*)(region);
    float* gh   = (float*)(region + 6291456);
    bf16*  SAB  = (bf16*) (region);                 // [N,512] bf16 = 4.2 MB

    if (ws_size < off) { k_sentinel<<<2048, 256, 0, stream>>>((float*)d_out, 44.f); return; }

    // ---- index canonicalize + CSR ----
    k_detidx<<<1, 64, 0, stream>>>(eidx, iflag);
    k_extidx<<<EE / 256, 256, 0, stream>>>(eidx, srcW, dstW, iflag);
    hipMemsetAsync(counts, 0, NN * 4, stream);
    k_count<<<EE / 256, 256, 0, stream>>>(dstW, counts);
    k_scan<<<1, 1024, 0, stream>>>(counts, offs, cursor);
    k_fill<<<EE / 256, 256, 0, stream>>>(dstW, srcW, cursor, pos, srcord);

    // ---- float canonicalize ----
    k_detect<<<1, 64, 0, stream>>>(d_in[1], dflag);
    auto CF = [&](int idx, float* dst, int n) {
        k_canon_f<<<(n + 255) / 256, 256, 0, stream>>>(d_in[idx], dst, n, dflag);
    };
    auto CB = [&](int idx, bf16* dst, int n) {
        k_canon_b<<<(n + 255) / 256, 256, 0, stream>>>(d_in[idx], dst, n, dflag);
    };
    k_canon_fb<<<(NN * HH + 255) / 256, 256, 0, stream>>>(d_in[0], out_f32, out_bf, NN * HH, dflag);
    k_canon_ea<<<(EE * EDD + 255) / 256, 256, 0, stream>>>(d_in[1], eaord, pos, dflag);
    k_canon_fb<<<(589824 + 255) / 256, 256, 0, stream>>>(d_in[5], preWc, preWbf, 589824, dflag);
    CF(3, encWc, 24576);   CF(4, encbc, 384);   CF(6, prebc, 1536);
    CF(8, postbc, 384);    CF(10, linbc, 384);  CF(13, bihc, 384);  CF(14, bhhc, 384);
    CF(16, em1bc, 256);    CF(18, em2bc, 128);  CF(20, eu1bc, 128); CF(22, eu2bc, 64);
    CB(7, postWbf, 196608); CB(9, linWbf, 49152);
    CB(11, WihBf, 49152);   CB(12, WhhBf, 49152);
    CB(15, em1Wbf, 65536);  CB(17, em2Wbf, 32768);
    CB(19, eu1Wbf, 24576);  CB(21, eu2Wbf, 8192);
    // repacks
    k_rep_node<<<(3 * 131072) / 256, 256, 0, stream>>>(preWbf, WnodeBf);
    k_rep_em1<<<65536 / 256, 256, 0, stream>>>(em1Wbf, Wem1Bf);
    k_ext_em1b<<<2, 256, 0, stream>>>(em1bc, em1ext);

    auto GEMM = [&](const bf16* A, int lda, const bf16* Wm, int ldw, const float* bias,
                    void* C, int ldc, int M, int Nout, int K, bool relu, int om) {
        dim3 grid(M / 64, Nout / 64);
        if (relu) {
            if (om) k_mgemm<true, 1><<<grid, 256, 0, stream>>>(A, lda, Wm, ldw, bias, C, ldc, K);
            else    k_mgemm<true, 0><<<grid, 256, 0, stream>>>(A, lda, Wm, ldw, bias, C, ldc, K);
        } else {
            if (om) k_mgemm<false, 1><<<grid, 256, 0, stream>>>(A, lda, Wm, ldw, bias, C, ldc, K);
            else    k_mgemm<false, 0><<<grid, 256, 0, stream>>>(A, lda, Wm, ldw, bias, C, ldc, K);
        }
    };

    for (int l = 0; l < 3; l++) {
        const float* preW_l  = preWc  + (size_t)l * 196608;
        const float* encW_l  = encWc  + (size_t)l * 8192;
        const float* encb_l  = encbc  + (size_t)l * 128;
        const float* preb_l  = prebc  + (size_t)l * 512;
        const bf16*  Wnode_l = WnodeBf + (size_t)l * 131072;
        const bf16*  postW_l = postWbf + (size_t)l * 65536;
        const float* postb_l = postbc + (size_t)l * 128;
        const bf16*  linW_l  = linWbf + (size_t)l * 16384;
        const float* linb_l  = linbc  + (size_t)l * 128;
        const bool last = (l == 2);

        // ---- PNA ----
        k_wcomb<<<THD, 64, 0, stream>>>(preW_l, encW_l, encb_l, preb_l, wcombBf, bcombx);
        GEMM(out_bf, HH, Wnode_l, 128, bcombx, PdPs, 1024, NN, 1024, HH, false, 0);
        k_qgemm<<<dim3(EE / 64, 2), 256, 0, stream>>>(eaord, wcombBf, Qord);
        k_agg<<<NN, 128, 0, stream>>>(PdPs, Qord, srcord, offs, aggX, aggS, aggM);
        k_postg<<<dim3(NN / 64, 4), 256, 0, stream>>>(out_bf, aggX, aggS, aggM,
                                                      postW_l, postb_l, ybf);
        GEMM(ybf, HH, linW_l, HH, linb_l, m_bf, HH, NN, HH, HH, true, 1);
        // ---- GRU ----
        GEMM(m_bf,   HH, WihBf, HH, bihc, gi, 384, NN, 384, HH, false, 0);
        GEMM(out_bf, HH, WhhBf, HH, bhhc, gh, 384, NN, 384, HH, false, 0);
        k_gru<<<NN * HH / 256, 256, 0, stream>>>(gi, gh, out_f32, out_bf,
                                                 last ? (float*)d_out : (float*)nullptr);
        // ---- edge update (merged SAB + fused chain; SAB now bf16) ----
        GEMM(out_bf, HH, Wem1Bf, 128, em1ext, SAB, 512, NN, 512, HH, false, 1);
        k_edge<<<EE / 64, 256, 0, stream>>>(SAB, em2Wbf, em2bc, eu1Wbf, eu1bc,
                                            eu2Wbf, eu2bc, srcW, dstW, pos,
                                            eaord, last ? (float*)d_out + 524288 : (float*)nullptr);
    }
}